// Round 2
// baseline (14005.693 us; speedup 1.0000x reference)
//
#include <hip/hip_runtime.h>

// Problem constants (B,S,H,NH,P) = (2,2048,1024,16,64)
#define B_ 2
#define S_ 2048
#define H_ 1024
#define NH_ 16
#define P_ 64

// XOR swizzle at float4 granularity, keyed on row>>2.
static __device__ __forceinline__ int swz64(int row, int p) {
  return row * 64 + ((((p >> 2) ^ (row >> 2)) & 15) << 2) + (p & 3);
}
static __device__ __forceinline__ int swz32(int row, int p) {
  return row * 32 + ((((p >> 2) ^ (row >> 2)) & 7) << 2) + (p & 3);
}

static __device__ __forceinline__ void fma4(float (&acc)[4], float s, const float4& v) {
  acc[0] += s * v.x; acc[1] += s * v.y; acc[2] += s * v.z; acc[3] += s * v.w;
}

// ---------------------------------------------------------------------------
// Kernel 1: QKV projection.  out_t[b][n][s][p] = sum_h x[b][s][h] * W[n][t][h][p]
// grid = B*NH*3*(S/64), block 256, tile 64(rows s) x 64(p), BK=32
// ---------------------------------------------------------------------------
__global__ __launch_bounds__(256) void qkv_kernel(
    const float* __restrict__ x, const float* __restrict__ W,
    float* __restrict__ Kb, float* __restrict__ Vb, float* __restrict__ Qb)
{
  __shared__ __align__(16) float As[64 * 32];  // x tile, row-major [s][k], swizzled
  __shared__ __align__(16) float Bs[32 * 64];  // W tile, k-major [k][p], linear

  int blk = blockIdx.x;
  const int it = blk & 31; blk >>= 5;
  const int t  = blk % 3;  blk /= 3;
  const int n  = blk & 15;
  const int b  = blk >> 4;
  const int s0 = it * 64;
  const int tid = threadIdx.x;
  const int tx = tid & 15, ty = tid >> 4;
  const int arow = tid >> 3, af = tid & 7;

  const float* Asrc = x + ((size_t)b * S_ + s0) * H_;
  const float* Bsrc = W + ((size_t)n * 3 + t) * H_ * P_;

  float acc[4][4] = {};

  for (int k0 = 0; k0 < H_; k0 += 32) {
    #pragma unroll
    for (int r = 0; r < 2; ++r) {
      int rr = arow + r * 32;
      *(float4*)&As[swz32(rr, af * 4)] =
          *(const float4*)(Asrc + (size_t)rr * H_ + k0 + af * 4);
    }
    #pragma unroll
    for (int r = 0; r < 2; ++r) {
      int idx4 = tid + r * 256;
      *(float4*)&Bs[idx4 * 4] = *(const float4*)(Bsrc + (size_t)k0 * P_ + idx4 * 4);
    }
    __syncthreads();
    #pragma unroll
    for (int k4 = 0; k4 < 8; ++k4) {
      float4 a[4], bq[4];
      #pragma unroll
      for (int i = 0; i < 4; ++i) a[i] = *(const float4*)&As[swz32(ty * 4 + i, k4 * 4)];
      #pragma unroll
      for (int q = 0; q < 4; ++q) bq[q] = *(const float4*)&Bs[(k4 * 4 + q) * 64 + tx * 4];
      #pragma unroll
      for (int i = 0; i < 4; ++i) {
        fma4(acc[i], a[i].x, bq[0]);
        fma4(acc[i], a[i].y, bq[1]);
        fma4(acc[i], a[i].z, bq[2]);
        fma4(acc[i], a[i].w, bq[3]);
      }
    }
    __syncthreads();
  }

  float* dstb = (t == 0) ? Kb : ((t == 1) ? Vb : Qb);
  float* dst = dstb + (((size_t)b * NH_ + n) * S_ + s0) * P_;
  #pragma unroll
  for (int i = 0; i < 4; ++i) {
    float4 v = make_float4(acc[i][0], acc[i][1], acc[i][2], acc[i][3]);
    *(float4*)(dst + (size_t)(ty * 4 + i) * P_ + tx * 4) = v;
  }
}

// ---------------------------------------------------------------------------
// Kernel 2: per-column (over i) online max / sum-exp of scores[i,j]=K_i·Q_j/8.
// One block (512 thr) per (b, n, j-tile of 64). Each thread: 2 rows x 4 cols.
// ---------------------------------------------------------------------------
__global__ __launch_bounds__(512, 4) void stats_kernel(
    const float* __restrict__ Kb, const float* __restrict__ Qb,
    float* __restrict__ cmax, float* __restrict__ csum)
{
  __shared__ __align__(16) float Qs[64 * 64];
  __shared__ __align__(16) float Ks[64 * 64];
  __shared__ __align__(16) float Ss[64 * 64];
  __shared__ float red[8 * 64];
  __shared__ float cm[64], cz[64], mn[64];

  int blk = blockIdx.x;
  const int jt = blk & 31; blk >>= 5;
  const int n = blk & 15;
  const int b = blk >> 4;
  const int tid = threadIdx.x;
  const int tx = tid & 15, ty = tid >> 4;   // ty 0..31
  const size_t bn = (size_t)b * NH_ + n;
  const int j0 = jt * 64;

  {
    const float* src = Qb + (bn * S_ + j0) * P_;
    #pragma unroll
    for (int r = 0; r < 2; ++r) {
      int idx4 = tid + r * 512;
      int row = idx4 >> 4, p0 = (idx4 & 15) << 2;
      *(float4*)&Qs[swz64(row, p0)] = *(const float4*)(src + row * P_ + p0);
    }
  }
  if (tid < 64) { cm[tid] = -3.0e38f; cz[tid] = 0.0f; }

  const int sub = tid >> 6;   // 0..7 : row-eighth for reduction
  const int jc = tid & 63;    // column

  for (int i0 = 0; i0 < S_; i0 += 64) {
    __syncthreads();   // prev reductions / initial staging ordered
    {
      const float* src = Kb + (bn * S_ + i0) * P_;
      #pragma unroll
      for (int r = 0; r < 2; ++r) {
        int idx4 = tid + r * 512;
        int row = idx4 >> 4, p0 = (idx4 & 15) << 2;
        *(float4*)&Ks[swz64(row, p0)] = *(const float4*)(src + row * P_ + p0);
      }
    }
    __syncthreads();

    float sc[2][4] = {};
    #pragma unroll
    for (int p4 = 0; p4 < 16; ++p4) {
      float4 ka[2], qa[4];
      #pragma unroll
      for (int i = 0; i < 2; ++i) ka[i] = *(const float4*)&Ks[swz64(ty * 2 + i, p4 * 4)];
      #pragma unroll
      for (int j = 0; j < 4; ++j) qa[j] = *(const float4*)&Qs[swz64(tx * 4 + j, p4 * 4)];
      #pragma unroll
      for (int i = 0; i < 2; ++i) {
        #pragma unroll
        for (int j = 0; j < 4; ++j) {
          sc[i][j] += ka[i].x * qa[j].x;
          sc[i][j] += ka[i].y * qa[j].y;
          sc[i][j] += ka[i].z * qa[j].z;
          sc[i][j] += ka[i].w * qa[j].w;
        }
      }
    }
    #pragma unroll
    for (int i = 0; i < 2; ++i) {
      float4 v = make_float4(sc[i][0] * 0.125f, sc[i][1] * 0.125f,
                             sc[i][2] * 0.125f, sc[i][3] * 0.125f);
      *(float4*)&Ss[swz64(ty * 2 + i, tx * 4)] = v;
    }
    __syncthreads();

    float lm = -3.0e38f;
    #pragma unroll
    for (int r = 0; r < 8; ++r) lm = fmaxf(lm, Ss[swz64(sub * 8 + r, jc)]);
    red[sub * 64 + jc] = lm;
    __syncthreads();
    if (tid < 64) {
      float m8 = red[tid];
      #pragma unroll
      for (int t = 1; t < 8; ++t) m8 = fmaxf(m8, red[t * 64 + tid]);
      mn[tid] = fmaxf(cm[tid], m8);
    }
    __syncthreads();
    const float mj = mn[jc];
    float ls = 0.0f;
    #pragma unroll
    for (int r = 0; r < 8; ++r) ls += __expf(Ss[swz64(sub * 8 + r, jc)] - mj);
    red[sub * 64 + jc] = ls;
    __syncthreads();
    if (tid < 64) {
      float ts = 0.0f;
      #pragma unroll
      for (int t = 0; t < 8; ++t) ts += red[t * 64 + tid];
      cz[tid] = cz[tid] * __expf(cm[tid] - mn[tid]) + ts;
      cm[tid] = mn[tid];
    }
  }
  __syncthreads();
  if (tid < 64) {
    cmax[bn * S_ + j0 + tid] = cm[tid];
    csum[bn * S_ + j0 + tid] = cz[tid];
  }
}

// ---------------------------------------------------------------------------
// Kernel 3: out[i,:] = sum_j w[i,j] * V[j,:];  w = exp(s-m_j)/Z_j or 1/S (masked).
// One block (512 thr) per (b, n, i-tile of 64). Each thread: 2 rows x 4 cols.
// ---------------------------------------------------------------------------
__global__ __launch_bounds__(512, 4) void av_kernel(
    const float* __restrict__ Kb, const float* __restrict__ Qb,
    const float* __restrict__ Vb,
    const float* __restrict__ cmax, const float* __restrict__ csum,
    const int* __restrict__ mask, float* __restrict__ hid)
{
  __shared__ __align__(16) float Ks[64 * 64];
  __shared__ __align__(16) float QWs[64 * 64];   // Q tile, reused as W tile
  __shared__ __align__(16) float Vs[64 * 64];    // k-major [j][p], linear
  __shared__ float ms[64], zi[64];
  __shared__ int mk[64];

  int blk = blockIdx.x;
  const int it = blk & 31; blk >>= 5;
  const int n = blk & 15;
  const int b = blk >> 4;
  const int tid = threadIdx.x;
  const int tx = tid & 15, ty = tid >> 4;   // ty 0..31
  const size_t bn = (size_t)b * NH_ + n;
  const int i0 = it * 64;

  {
    const float* src = Kb + (bn * S_ + i0) * P_;
    #pragma unroll
    for (int r = 0; r < 2; ++r) {
      int idx4 = tid + r * 512;
      int row = idx4 >> 4, p0 = (idx4 & 15) << 2;
      *(float4*)&Ks[swz64(row, p0)] = *(const float4*)(src + row * P_ + p0);
    }
  }
  float out[2][4] = {};

  for (int j0 = 0; j0 < S_; j0 += 64) {
    __syncthreads();  // previous PV reads (and initial Ks staging) complete
    {
      const float* qsrc = Qb + (bn * S_ + j0) * P_;
      const float* vsrc = Vb + (bn * S_ + j0) * P_;
      #pragma unroll
      for (int r = 0; r < 2; ++r) {
        int idx4 = tid + r * 512;
        int row = idx4 >> 4, p0 = (idx4 & 15) << 2;
        *(float4*)&QWs[swz64(row, p0)] = *(const float4*)(qsrc + row * P_ + p0);
        *(float4*)&Vs[row * 64 + p0]   = *(const float4*)(vsrc + row * P_ + p0);
      }
      if (tid < 64) {
        ms[tid] = cmax[bn * S_ + j0 + tid];
        zi[tid] = 1.0f / csum[bn * S_ + j0 + tid];
        mk[tid] = mask[(size_t)b * S_ + j0 + tid];
      }
    }
    __syncthreads();

    float sc[2][4] = {};
    #pragma unroll
    for (int p4 = 0; p4 < 16; ++p4) {
      float4 ka[2], qa[4];
      #pragma unroll
      for (int i = 0; i < 2; ++i) ka[i] = *(const float4*)&Ks[swz64(ty * 2 + i, p4 * 4)];
      #pragma unroll
      for (int j = 0; j < 4; ++j) qa[j] = *(const float4*)&QWs[swz64(tx * 4 + j, p4 * 4)];
      #pragma unroll
      for (int i = 0; i < 2; ++i) {
        #pragma unroll
        for (int j = 0; j < 4; ++j) {
          sc[i][j] += ka[i].x * qa[j].x;
          sc[i][j] += ka[i].y * qa[j].y;
          sc[i][j] += ka[i].z * qa[j].z;
          sc[i][j] += ka[i].w * qa[j].w;
        }
      }
    }
    float wv[2][4];
    #pragma unroll
    for (int i = 0; i < 2; ++i) {
      #pragma unroll
      for (int j = 0; j < 4; ++j) {
        int jj = tx * 4 + j;
        float s = sc[i][j] * 0.125f;
        wv[i][j] = mk[jj] ? (__expf(s - ms[jj]) * zi[jj]) : (1.0f / 2048.0f);
      }
    }
    __syncthreads();  // all Q reads of QWs done before overwrite
    #pragma unroll
    for (int i = 0; i < 2; ++i) {
      float4 v = make_float4(wv[i][0], wv[i][1], wv[i][2], wv[i][3]);
      *(float4*)&QWs[swz64(ty * 2 + i, tx * 4)] = v;
    }
    __syncthreads();

    #pragma unroll
    for (int j4 = 0; j4 < 16; ++j4) {
      float4 wa[2], vv[4];
      #pragma unroll
      for (int i = 0; i < 2; ++i) wa[i] = *(const float4*)&QWs[swz64(ty * 2 + i, j4 * 4)];
      #pragma unroll
      for (int q = 0; q < 4; ++q) vv[q] = *(const float4*)&Vs[(j4 * 4 + q) * 64 + tx * 4];
      #pragma unroll
      for (int i = 0; i < 2; ++i) {
        fma4(out[i], wa[i].x, vv[0]);
        fma4(out[i], wa[i].y, vv[1]);
        fma4(out[i], wa[i].z, vv[2]);
        fma4(out[i], wa[i].w, vv[3]);
      }
    }
  }

  float* dst = hid + ((size_t)b * S_ + i0) * H_ + n * 64;
  #pragma unroll
  for (int i = 0; i < 2; ++i) {
    float4 v = make_float4(out[i][0], out[i][1], out[i][2], out[i][3]);
    *(float4*)(dst + (size_t)(ty * 2 + i) * H_ + tx * 4) = v;
  }
}

// ---------------------------------------------------------------------------
// Kernel 4: out = hidden @ Wl.T + bl.   grid = (B*S/64)*(H/64)
// ---------------------------------------------------------------------------
__global__ __launch_bounds__(256) void final_kernel(
    const float* __restrict__ hid, const float* __restrict__ Wl,
    const float* __restrict__ bl, float* __restrict__ out)
{
  __shared__ __align__(16) float As[64 * 32];
  __shared__ __align__(16) float Bs[64 * 32];  // Wl rows (o), row-major over k
  int blk = blockIdx.x;
  const int ot = blk & 15;
  const int rt = blk >> 4;
  const int r0 = rt * 64, o0 = ot * 64;
  const int tid = threadIdx.x;
  const int tx = tid & 15, ty = tid >> 4;
  const int arow = tid >> 3, af = tid & 7;

  float acc[4][4] = {};
  for (int k0 = 0; k0 < H_; k0 += 32) {
    #pragma unroll
    for (int r = 0; r < 2; ++r) {
      int rr = arow + r * 32;
      *(float4*)&As[swz32(rr, af * 4)] =
          *(const float4*)(hid + (size_t)(r0 + rr) * H_ + k0 + af * 4);
      *(float4*)&Bs[swz32(rr, af * 4)] =
          *(const float4*)(Wl + (size_t)(o0 + rr) * H_ + k0 + af * 4);
    }
    __syncthreads();
    #pragma unroll
    for (int k4 = 0; k4 < 8; ++k4) {
      float4 a[4], w[4];
      #pragma unroll
      for (int i = 0; i < 4; ++i) a[i] = *(const float4*)&As[swz32(ty * 4 + i, k4 * 4)];
      #pragma unroll
      for (int j = 0; j < 4; ++j) w[j] = *(const float4*)&Bs[swz32(tx * 4 + j, k4 * 4)];
      #pragma unroll
      for (int i = 0; i < 4; ++i) {
        #pragma unroll
        for (int j = 0; j < 4; ++j) {
          acc[i][j] += a[i].x * w[j].x;
          acc[i][j] += a[i].y * w[j].y;
          acc[i][j] += a[i].z * w[j].z;
          acc[i][j] += a[i].w * w[j].w;
        }
      }
    }
    __syncthreads();
  }
  const float4 bv = *(const float4*)(bl + o0 + tx * 4);
  #pragma unroll
  for (int i = 0; i < 4; ++i) {
    float4 v = make_float4(acc[i][0] + bv.x, acc[i][1] + bv.y,
                           acc[i][2] + bv.z, acc[i][3] + bv.w);
    *(float4*)(out + (size_t)(r0 + ty * 4 + i) * H_ + o0 + tx * 4) = v;
  }
}

// ---------------------------------------------------------------------------
extern "C" void kernel_launch(void* const* d_in, const int* in_sizes, int n_in,
                              void* d_out, int out_size, void* d_ws, size_t ws_size,
                              hipStream_t stream) {
  const float* x    = (const float*)d_in[0];
  const int*   mask = (const int*)d_in[1];
  const float* W    = (const float*)d_in[2];
  const float* Wl   = (const float*)d_in[3];
  const float* bl   = (const float*)d_in[4];
  float* out = (float*)d_out;

  const size_t SZ_KVQ = (size_t)B_ * NH_ * S_ * P_;   // 4,194,304
  const size_t SZ_COL = (size_t)B_ * NH_ * S_;        // 65,536
  float* ws = (float*)d_ws;
  float* Kb   = ws;
  float* Vb   = Kb + SZ_KVQ;
  float* Qb   = Vb + SZ_KVQ;
  float* cmax = Qb + SZ_KVQ;
  float* csum = cmax + SZ_COL;
  float* hid  = csum + SZ_COL;

  qkv_kernel  <<<B_ * NH_ * 3 * (S_ / 64), 256, 0, stream>>>(x, W, Kb, Vb, Qb);
  stats_kernel<<<B_ * NH_ * (S_ / 64),     512, 0, stream>>>(Kb, Qb, cmax, csum);
  av_kernel   <<<B_ * NH_ * (S_ / 64),     512, 0, stream>>>(Kb, Qb, Vb, cmax, csum, mask, hid);
  final_kernel<<<(B_ * S_ / 64) * (H_ / 64), 256, 0, stream>>>(hid, Wl, bl, out);
}

// Round 3
// 1012.835 us; speedup vs baseline: 13.8282x; 13.8282x over previous
//
#include <hip/hip_runtime.h>

// Problem constants (B,S,H,NH,P) = (2,2048,1024,16,64)
#define B_ 2
#define S_ 2048
#define H_ 1024
#define NH_ 16
#define P_ 64

using f32x4 = __attribute__((ext_vector_type(4))) float;
using i32x4 = __attribute__((ext_vector_type(4))) int;
using s16x8 = __attribute__((ext_vector_type(8))) short;
using s16x4 = __attribute__((ext_vector_type(4))) short;

static __device__ __forceinline__ short f2bf(float f) {
  unsigned u = __float_as_uint(f);
  unsigned r = (u + 0x7fffu + ((u >> 16) & 1u)) >> 16;
  return (short)r;
}
static __device__ __forceinline__ float bf2f(short s) {
  return __uint_as_float(((unsigned)(unsigned short)s) << 16);
}
static __device__ __forceinline__ s16x8 ld8(const short* p) { return *(const s16x8*)p; }

// bf16x3 fused: c += ahi*bhi + ahi*blo + alo*bhi
static __device__ __forceinline__ f32x4 mm3(s16x8 ah, s16x8 al, s16x8 bh, s16x8 bl, f32x4 c) {
  c = __builtin_amdgcn_mfma_f32_16x16x32_bf16(ah, bh, c, 0, 0, 0);
  c = __builtin_amdgcn_mfma_f32_16x16x32_bf16(ah, bl, c, 0, 0, 0);
  c = __builtin_amdgcn_mfma_f32_16x16x32_bf16(al, bh, c, 0, 0, 0);
  return c;
}

// XOR swizzle helpers for fp32 tiles (qkv/final kernels, unchanged from R0)
static __device__ __forceinline__ int swz32(int row, int p) {
  return row * 32 + ((((p >> 2) ^ (row >> 2)) & 7) << 2) + (p & 3);
}

static __device__ __forceinline__ void fma4(float (&acc)[4], float s, const float4& v) {
  acc[0] += s * v.x; acc[1] += s * v.y; acc[2] += s * v.z; acc[3] += s * v.w;
}

// ---------------------------------------------------------------------------
// Kernel 1: QKV projection (fp32 compute, R0 structure). Epilogue splits to
// bf16 hi/lo: K,Q as [bn][s][p]; V transposed as [bn][p][s].
// ---------------------------------------------------------------------------
__global__ __launch_bounds__(256) void qkv_kernel(
    const float* __restrict__ x, const float* __restrict__ W,
    short* __restrict__ Khi, short* __restrict__ Klo,
    short* __restrict__ Qhi, short* __restrict__ Qlo,
    short* __restrict__ VThi, short* __restrict__ VTlo)
{
  __shared__ __align__(16) float As[64 * 32];
  __shared__ __align__(16) float Bs[32 * 64];

  int blk = blockIdx.x;
  const int it = blk & 31; blk >>= 5;
  const int t  = blk % 3;  blk /= 3;
  const int n  = blk & 15;
  const int b  = blk >> 4;
  const int s0 = it * 64;
  const int tid = threadIdx.x;
  const int tx = tid & 15, ty = tid >> 4;
  const int arow = tid >> 3, af = tid & 7;
  const int bn = b * NH_ + n;

  const float* Asrc = x + ((size_t)b * S_ + s0) * H_;
  const float* Bsrc = W + ((size_t)n * 3 + t) * H_ * P_;

  float acc[4][4] = {};

  for (int k0 = 0; k0 < H_; k0 += 32) {
    #pragma unroll
    for (int r = 0; r < 2; ++r) {
      int rr = arow + r * 32;
      *(float4*)&As[swz32(rr, af * 4)] =
          *(const float4*)(Asrc + (size_t)rr * H_ + k0 + af * 4);
    }
    #pragma unroll
    for (int r = 0; r < 2; ++r) {
      int idx4 = tid + r * 256;
      *(float4*)&Bs[idx4 * 4] = *(const float4*)(Bsrc + (size_t)k0 * P_ + idx4 * 4);
    }
    __syncthreads();
    #pragma unroll
    for (int k4 = 0; k4 < 8; ++k4) {
      float4 a[4], bq[4];
      #pragma unroll
      for (int i = 0; i < 4; ++i) a[i] = *(const float4*)&As[swz32(ty * 4 + i, k4 * 4)];
      #pragma unroll
      for (int q2 = 0; q2 < 4; ++q2) bq[q2] = *(const float4*)&Bs[(k4 * 4 + q2) * 64 + tx * 4];
      #pragma unroll
      for (int i = 0; i < 4; ++i) {
        fma4(acc[i], a[i].x, bq[0]);
        fma4(acc[i], a[i].y, bq[1]);
        fma4(acc[i], a[i].z, bq[2]);
        fma4(acc[i], a[i].w, bq[3]);
      }
    }
    __syncthreads();
  }

  if (t == 0 || t == 2) {
    short* dh = (t == 0) ? Khi : Qhi;
    short* dl = (t == 0) ? Klo : Qlo;
    #pragma unroll
    for (int i = 0; i < 4; ++i) {
      s16x4 h4, l4;
      #pragma unroll
      for (int c = 0; c < 4; ++c) {
        float v = acc[i][c];
        short hh = f2bf(v);
        h4[c] = hh;
        l4[c] = f2bf(v - bf2f(hh));
      }
      size_t off = ((size_t)bn * S_ + (s0 + ty * 4 + i)) * P_ + tx * 4;
      *(s16x4*)(dh + off) = h4;
      *(s16x4*)(dl + off) = l4;
    }
  } else {
    // V: store transposed [bn][p][s]
    #pragma unroll
    for (int c = 0; c < 4; ++c) {
      s16x4 h4, l4;
      #pragma unroll
      for (int i = 0; i < 4; ++i) {
        float v = acc[i][c];
        short hh = f2bf(v);
        h4[i] = hh;
        l4[i] = f2bf(v - bf2f(hh));
      }
      size_t off = ((size_t)bn * P_ + (tx * 4 + c)) * S_ + s0 + ty * 4;
      *(s16x4*)(VThi + off) = h4;
      *(s16x4*)(VTlo + off) = l4;
    }
  }
}

// ---------------------------------------------------------------------------
// Kernel 2: column stats via MFMA. Scores D[j][i] = mfma(Q-frag, K-frag).
// Block = 256 thr (4 waves, 2x2 over (j,i)), j-tile 64 fixed, i streams.
// ---------------------------------------------------------------------------
__global__ __launch_bounds__(256) void stats_kernel(
    const short* __restrict__ Khi, const short* __restrict__ Klo,
    const short* __restrict__ Qhi, const short* __restrict__ Qlo,
    float* __restrict__ cmax, float* __restrict__ csuminv)
{
  __shared__ float redA[128], redB[128], mn[64], cm[64], cz[64];
  const int tid = threadIdx.x;
  const int bid = blockIdx.x;
  const int j0 = (bid & 31) * 64;
  const int bn = bid >> 5;
  const int w = tid >> 6, lane = tid & 63, q = lane >> 4, fr = lane & 15;
  const int jb = 32 * (w & 1), ih = w >> 1, ib0 = 32 * ih;

  if (tid < 64) { cm[tid] = -3.0e38f; cz[tid] = 0.0f; }

  // preload Q a-frags (fixed j-tile)
  s16x8 qh[2][2], ql[2][2];
  #pragma unroll
  for (int jt = 0; jt < 2; ++jt)
    #pragma unroll
    for (int ks = 0; ks < 2; ++ks) {
      size_t off = ((size_t)bn * S_ + (j0 + jb + 16 * jt + fr)) * P_ + 8 * q + 32 * ks;
      qh[jt][ks] = ld8(Qhi + off);
      ql[jt][ks] = ld8(Qlo + off);
    }
  __syncthreads();

  s16x8 kAh[2][2], kAl[2][2], kBh[2][2], kBl[2][2];

  auto loadK = [&](s16x8 (&khf)[2][2], s16x8 (&klf)[2][2], int i0) {
    #pragma unroll
    for (int it = 0; it < 2; ++it)
      #pragma unroll
      for (int ks = 0; ks < 2; ++ks) {
        size_t off = ((size_t)bn * S_ + (i0 + ib0 + 16 * it + fr)) * P_ + 8 * q + 32 * ks;
        khf[it][ks] = ld8(Khi + off);
        klf[it][ks] = ld8(Klo + off);
      }
  };

  auto statStep = [&](s16x8 (&khf)[2][2], s16x8 (&klf)[2][2]) {
    f32x4 sc[2][2] = {};
    #pragma unroll
    for (int ks = 0; ks < 2; ++ks)
      #pragma unroll
      for (int jt = 0; jt < 2; ++jt)
        #pragma unroll
        for (int it = 0; it < 2; ++it)
          sc[jt][it] = mm3(qh[jt][ks], ql[jt][ks], khf[it][ks], klf[it][ks], sc[jt][it]);
    #pragma unroll
    for (int jt = 0; jt < 2; ++jt)
      #pragma unroll
      for (int it = 0; it < 2; ++it)
        #pragma unroll
        for (int c = 0; c < 4; ++c)
          sc[jt][it][c] *= 0.125f;

    // per-lane max over it; then reduce across the 16 fr-lanes (same j)
    f32x4 tm[2];
    #pragma unroll
    for (int jt = 0; jt < 2; ++jt) {
      #pragma unroll
      for (int c = 0; c < 4; ++c)
        tm[jt][c] = fmaxf(sc[jt][0][c], sc[jt][1][c]);
      #pragma unroll
      for (int m = 1; m <= 8; m <<= 1)
        #pragma unroll
        for (int c = 0; c < 4; ++c)
          tm[jt][c] = fmaxf(tm[jt][c], __shfl_xor(tm[jt][c], m, 64));
    }
    if (fr == 0) {
      #pragma unroll
      for (int jt = 0; jt < 2; ++jt)
        *(f32x4*)&redA[ih * 64 + jb + 16 * jt + 4 * q] = tm[jt];
    }
    __syncthreads();
    if (tid < 64) mn[tid] = fmaxf(cm[tid], fmaxf(redA[tid], redA[64 + tid]));
    __syncthreads();
    #pragma unroll
    for (int jt = 0; jt < 2; ++jt) {
      f32x4 mv = *(const f32x4*)&mn[jb + 16 * jt + 4 * q];
      f32x4 p;
      #pragma unroll
      for (int c = 0; c < 4; ++c)
        p[c] = __expf(sc[jt][0][c] - mv[c]) + __expf(sc[jt][1][c] - mv[c]);
      #pragma unroll
      for (int m = 1; m <= 8; m <<= 1)
        #pragma unroll
        for (int c = 0; c < 4; ++c)
          p[c] += __shfl_xor(p[c], m, 64);
      if (fr == 0)
        *(f32x4*)&redB[ih * 64 + jb + 16 * jt + 4 * q] = p;
    }
    __syncthreads();
    if (tid < 64) {
      cz[tid] = cz[tid] * __expf(cm[tid] - mn[tid]) + redB[tid] + redB[64 + tid];
      cm[tid] = mn[tid];
    }
  };

  loadK(kAh, kAl, 0);
  for (int i0 = 0; i0 < S_; i0 += 128) {
    loadK(kBh, kBl, i0 + 64);
    statStep(kAh, kAl);
    loadK(kAh, kAl, (i0 + 128) & (S_ - 1));
    statStep(kBh, kBl);
  }
  if (tid < 64) {
    cmax[(size_t)bn * S_ + j0 + tid] = cm[tid];
    csuminv[(size_t)bn * S_ + j0 + tid] = 1.0f / cz[tid];
  }
}

// ---------------------------------------------------------------------------
// Kernel 3: AV pass via MFMA. i-tile (64 output rows) fixed; j streams.
// scores D[j][i] = mfma(Q,K); w -> LDS [i][j] (swizzled); PV D'[p][i] =
// mfma(V^T, w). Writes hid [B][S][H] fp32.
// ---------------------------------------------------------------------------
__global__ __launch_bounds__(256) void av_kernel(
    const short* __restrict__ Khi, const short* __restrict__ Klo,
    const short* __restrict__ Qhi, const short* __restrict__ Qlo,
    const short* __restrict__ VThi, const short* __restrict__ VTlo,
    const float* __restrict__ cmax, const float* __restrict__ csuminv,
    const int* __restrict__ mask, float* __restrict__ hid)
{
  __shared__ short whi[64 * 64];
  __shared__ short wlo[64 * 64];
  const int tid = threadIdx.x;
  const int bid = blockIdx.x;
  const int i0 = (bid & 31) * 64;
  const int bn = bid >> 5;
  const int b = bn >> 4, n = bn & 15;
  const int w = tid >> 6, lane = tid & 63, q = lane >> 4, fr = lane & 15;
  const int jb = 32 * (w & 1), ih = w >> 1, ib = 32 * ih, pb = jb;
  const float INV_S = 1.0f / 2048.0f;

  // preload K b-frags (fixed i-tile)
  s16x8 kh[2][2], kl[2][2];
  #pragma unroll
  for (int it = 0; it < 2; ++it)
    #pragma unroll
    for (int ks = 0; ks < 2; ++ks) {
      size_t off = ((size_t)bn * S_ + (i0 + ib + 16 * it + fr)) * P_ + 8 * q + 32 * ks;
      kh[it][ks] = ld8(Khi + off);
      kl[it][ks] = ld8(Klo + off);
    }

  f32x4 opv[2][2] = {};

  for (int j0 = 0; j0 < S_; j0 += 64) {
    // Q a-frags for this j-tile
    s16x8 aqh[2][2], aql[2][2];
    #pragma unroll
    for (int jt = 0; jt < 2; ++jt)
      #pragma unroll
      for (int ks = 0; ks < 2; ++ks) {
        size_t off = ((size_t)bn * S_ + (j0 + jb + 16 * jt + fr)) * P_ + 8 * q + 32 * ks;
        aqh[jt][ks] = ld8(Qhi + off);
        aql[jt][ks] = ld8(Qlo + off);
      }
    f32x4 sc[2][2] = {};
    #pragma unroll
    for (int ks = 0; ks < 2; ++ks)
      #pragma unroll
      for (int jt = 0; jt < 2; ++jt)
        #pragma unroll
        for (int it = 0; it < 2; ++it)
          sc[jt][it] = mm3(aqh[jt][ks], aql[jt][ks], kh[it][ks], kl[it][ks], sc[jt][it]);

    __syncthreads();  // prev PV reads of w-LDS complete before overwrite

    #pragma unroll
    for (int jt = 0; jt < 2; ++jt) {
      const int jq = j0 + jb + 16 * jt + 4 * q;
      f32x4 mj = *(const f32x4*)(cmax + (size_t)bn * S_ + jq);
      f32x4 zj = *(const f32x4*)(csuminv + (size_t)bn * S_ + jq);
      i32x4 mk = *(const i32x4*)(mask + (size_t)b * S_ + jq);
      #pragma unroll
      for (int it = 0; it < 2; ++it) {
        s16x4 h4, l4;
        #pragma unroll
        for (int c = 0; c < 4; ++c) {
          float s = sc[jt][it][c] * 0.125f;
          float wv = (mk[c] != 0) ? __expf(s - mj[c]) * zj[c] : INV_S;
          short hh = f2bf(wv);
          h4[c] = hh;
          l4[c] = f2bf(wv - bf2f(hh));
        }
        int irow = ib + 16 * it + fr;
        int addr = (irow * 128 + (jb + 16 * jt + 4 * q) * 2) ^ ((irow & 7) << 4);
        *(s16x4*)((char*)whi + addr) = h4;
        *(s16x4*)((char*)wlo + addr) = l4;
      }
    }
    __syncthreads();  // w ready

    #pragma unroll
    for (int ks2 = 0; ks2 < 2; ++ks2) {
      s16x8 vh[2], vl[2], wh[2], wl2[2];
      #pragma unroll
      for (int pt = 0; pt < 2; ++pt) {
        size_t off = ((size_t)bn * P_ + (pb + 16 * pt + fr)) * S_ + j0 + 32 * ks2 + 8 * q;
        vh[pt] = ld8(VThi + off);
        vl[pt] = ld8(VTlo + off);
      }
      #pragma unroll
      for (int it = 0; it < 2; ++it) {
        int irow = ib + 16 * it + fr;
        int addr = (irow * 128 + 64 * ks2 + 16 * q) ^ ((irow & 7) << 4);
        wh[it]  = *(const s16x8*)((const char*)whi + addr);
        wl2[it] = *(const s16x8*)((const char*)wlo + addr);
      }
      #pragma unroll
      for (int pt = 0; pt < 2; ++pt)
        #pragma unroll
        for (int it = 0; it < 2; ++it)
          opv[pt][it] = mm3(vh[pt], vl[pt], wh[it], wl2[it], opv[pt][it]);
    }
  }

  #pragma unroll
  for (int pt = 0; pt < 2; ++pt)
    #pragma unroll
    for (int it = 0; it < 2; ++it) {
      int srow = i0 + ib + 16 * it + fr;
      int hcol = n * P_ + pb + 16 * pt + 4 * q;
      *(f32x4*)(hid + ((size_t)b * S_ + srow) * H_ + hcol) = opv[pt][it];
    }
}

// ---------------------------------------------------------------------------
// Kernel 4: out = hidden @ Wl.T + bl  (fp32, R0 structure)
// ---------------------------------------------------------------------------
__global__ __launch_bounds__(256) void final_kernel(
    const float* __restrict__ hid, const float* __restrict__ Wl,
    const float* __restrict__ bl, float* __restrict__ out)
{
  __shared__ __align__(16) float As[64 * 32];
  __shared__ __align__(16) float Bs[64 * 32];
  int blk = blockIdx.x;
  const int ot = blk & 15;
  const int rt = blk >> 4;
  const int r0 = rt * 64, o0 = ot * 64;
  const int tid = threadIdx.x;
  const int tx = tid & 15, ty = tid >> 4;
  const int arow = tid >> 3, af = tid & 7;

  float acc[4][4] = {};
  for (int k0 = 0; k0 < H_; k0 += 32) {
    #pragma unroll
    for (int r = 0; r < 2; ++r) {
      int rr = arow + r * 32;
      *(float4*)&As[swz32(rr, af * 4)] =
          *(const float4*)(hid + (size_t)(r0 + rr) * H_ + k0 + af * 4);
      *(float4*)&Bs[swz32(rr, af * 4)] =
          *(const float4*)(Wl + (size_t)(o0 + rr) * H_ + k0 + af * 4);
    }
    __syncthreads();
    #pragma unroll
    for (int k4 = 0; k4 < 8; ++k4) {
      float4 a[4], wq[4];
      #pragma unroll
      for (int i = 0; i < 4; ++i) a[i] = *(const float4*)&As[swz32(ty * 4 + i, k4 * 4)];
      #pragma unroll
      for (int j = 0; j < 4; ++j) wq[j] = *(const float4*)&Bs[swz32(tx * 4 + j, k4 * 4)];
      #pragma unroll
      for (int i = 0; i < 4; ++i) {
        #pragma unroll
        for (int j = 0; j < 4; ++j) {
          acc[i][j] += a[i].x * wq[j].x;
          acc[i][j] += a[i].y * wq[j].y;
          acc[i][j] += a[i].z * wq[j].z;
          acc[i][j] += a[i].w * wq[j].w;
        }
      }
    }
    __syncthreads();
  }
  const float4 bv = *(const float4*)(bl + o0 + tx * 4);
  #pragma unroll
  for (int i = 0; i < 4; ++i) {
    float4 v = make_float4(acc[i][0] + bv.x, acc[i][1] + bv.y,
                           acc[i][2] + bv.z, acc[i][3] + bv.w);
    *(float4*)(out + (size_t)(r0 + ty * 4 + i) * H_ + o0 + tx * 4) = v;
  }
}

// ---------------------------------------------------------------------------
extern "C" void kernel_launch(void* const* d_in, const int* in_sizes, int n_in,
                              void* d_out, int out_size, void* d_ws, size_t ws_size,
                              hipStream_t stream) {
  const float* x    = (const float*)d_in[0];
  const int*   mask = (const int*)d_in[1];
  const float* W    = (const float*)d_in[2];
  const float* Wl   = (const float*)d_in[3];
  const float* bl   = (const float*)d_in[4];
  float* out = (float*)d_out;

  const size_t SZ = (size_t)B_ * NH_ * S_ * P_;   // 4,194,304 elems
  const size_t SZ_COL = (size_t)B_ * NH_ * S_;    // 65,536
  short* Khi  = (short*)d_ws;
  short* Klo  = Khi + SZ;
  short* Qhi  = Klo + SZ;
  short* Qlo  = Qhi + SZ;
  short* VThi = Qlo + SZ;
  short* VTlo = VThi + SZ;
  float* cmax    = (float*)(VTlo + SZ);
  float* csuminv = cmax + SZ_COL;
  float* hid     = csuminv + SZ_COL;
  // total = 6*8.39MB + 0.5MB + 16.8MB ~= 67.6 MB

  qkv_kernel  <<<B_ * NH_ * 3 * (S_ / 64), 256, 0, stream>>>(
      x, W, Khi, Klo, Qhi, Qlo, VThi, VTlo);
  stats_kernel<<<B_ * NH_ * (S_ / 64), 256, 0, stream>>>(
      Khi, Klo, Qhi, Qlo, cmax, csuminv);
  av_kernel   <<<B_ * NH_ * (S_ / 64), 256, 0, stream>>>(
      Khi, Klo, Qhi, Qlo, VThi, VTlo, cmax, csuminv, mask, hid);
  final_kernel<<<(B_ * S_ / 64) * (H_ / 64), 256, 0, stream>>>(hid, Wl, bl, out);
}

// Round 4
// 912.841 us; speedup vs baseline: 15.3430x; 1.1095x over previous
//
#include <hip/hip_runtime.h>

// Problem constants (B,S,H,NH,P) = (2,2048,1024,16,64)
#define B_ 2
#define S_ 2048
#define H_ 1024
#define NH_ 16
#define P_ 64

using f32x4 = __attribute__((ext_vector_type(4))) float;
using i32x4 = __attribute__((ext_vector_type(4))) int;
using s16x8 = __attribute__((ext_vector_type(8))) short;
using s16x4 = __attribute__((ext_vector_type(4))) short;

static __device__ __forceinline__ short f2bf(float f) {
  unsigned u = __float_as_uint(f);
  unsigned r = (u + 0x7fffu + ((u >> 16) & 1u)) >> 16;
  return (short)r;
}
static __device__ __forceinline__ float bf2f(short s) {
  return __uint_as_float(((unsigned)(unsigned short)s) << 16);
}
static __device__ __forceinline__ s16x8 ld8(const short* p) { return *(const s16x8*)p; }
static __device__ __forceinline__ f32x4 ld4f(const float* p) { return *(const f32x4*)p; }

// bf16x3 fused: c += ahi*bhi + ahi*blo + alo*bhi
static __device__ __forceinline__ f32x4 mm3(s16x8 ah, s16x8 al, s16x8 bh, s16x8 bl, f32x4 c) {
  c = __builtin_amdgcn_mfma_f32_16x16x32_bf16(ah, bh, c, 0, 0, 0);
  c = __builtin_amdgcn_mfma_f32_16x16x32_bf16(ah, bl, c, 0, 0, 0);
  c = __builtin_amdgcn_mfma_f32_16x16x32_bf16(al, bh, c, 0, 0, 0);
  return c;
}

// ---------------------------------------------------------------------------
// Prep A: transpose+split W [NH][3][H][P] fp32 -> Wt hi/lo [NH][3][P][H] bf16
// grid = NH*3*(H/64) = 768 blocks, 256 thr
// ---------------------------------------------------------------------------
__global__ __launch_bounds__(256) void tw_kernel(
    const float* __restrict__ W, short* __restrict__ WtHi, short* __restrict__ WtLo)
{
  __shared__ float T[64 * 65];
  const int tid = threadIdx.x;
  const int nt = blockIdx.x >> 4;
  const int h0 = (blockIdx.x & 15) * 64;
  const float* src = W + (size_t)nt * H_ * P_ + (size_t)h0 * P_;
  #pragma unroll
  for (int r = 0; r < 4; ++r) {
    int idx = tid + r * 256;
    int h = idx >> 4, p4 = (idx & 15) << 2;
    f32x4 v = ld4f(src + (size_t)h * P_ + p4);
    #pragma unroll
    for (int i = 0; i < 4; ++i) T[(p4 + i) * 65 + h] = v[i];
  }
  __syncthreads();
  short* dh = WtHi + (size_t)nt * P_ * H_;
  short* dl = WtLo + (size_t)nt * P_ * H_;
  #pragma unroll
  for (int r = 0; r < 4; ++r) {
    int idx = tid + r * 256;
    int p = idx >> 4, h4 = (idx & 15) << 2;
    s16x4 hv, lv;
    #pragma unroll
    for (int i = 0; i < 4; ++i) {
      float f = T[p * 65 + h4 + i];
      short hh = f2bf(f);
      hv[i] = hh;
      lv[i] = f2bf(f - bf2f(hh));
    }
    *(s16x4*)(dh + (size_t)p * H_ + h0 + h4) = hv;
    *(s16x4*)(dl + (size_t)p * H_ + h0 + h4) = lv;
  }
}

// ---------------------------------------------------------------------------
// Prep B: split Wl [H][H] fp32 -> hi/lo bf16 (same layout). 1024x256 exact.
// ---------------------------------------------------------------------------
__global__ __launch_bounds__(256) void swl_kernel(
    const float* __restrict__ Wl, short* __restrict__ WlHi, short* __restrict__ WlLo)
{
  int idx = blockIdx.x * 256 + threadIdx.x;   // 0..262143 float4s
  f32x4 v = ((const f32x4*)Wl)[idx];
  s16x4 hv, lv;
  #pragma unroll
  for (int i = 0; i < 4; ++i) {
    short hh = f2bf(v[i]);
    hv[i] = hh;
    lv[i] = f2bf(v[i] - bf2f(hh));
  }
  ((s16x4*)WlHi)[idx] = hv;
  ((s16x4*)WlLo)[idx] = lv;
}

// ---------------------------------------------------------------------------
// Kernel 1: QKV projection via MFMA bf16x3. Block=(b,n,s-tile 64), 4 waves,
// wave w owns s-subtile 16. x converted to bf16 hi/lo in-register.
// K,Q: D[p][s] = mfma(Wt, x) -> K/Q[bn][s][p] hi+lo.
// V:   D[s][p] = mfma(x, Wt) -> VT[bn][p][s] hi only.
// ---------------------------------------------------------------------------
__global__ __launch_bounds__(256) void qkv_kernel(
    const float* __restrict__ x,
    const short* __restrict__ WtHi, const short* __restrict__ WtLo,
    short* __restrict__ Khi, short* __restrict__ Klo,
    short* __restrict__ Qhi, short* __restrict__ Qlo,
    short* __restrict__ VThi)
{
  int blk = blockIdx.x;
  const int st = blk & 31; blk >>= 5;
  const int n = blk & 15;
  const int b = blk >> 4;
  const int s0 = st * 64;
  const int tid = threadIdx.x;
  const int w = tid >> 6, lane = tid & 63, q = lane >> 4, fr = lane & 15;
  const int bn = b * NH_ + n;

  f32x4 accK[4] = {}, accQ[4] = {}, accV[4] = {};
  const float* xrow = x + ((size_t)b * S_ + s0 + 16 * w + fr) * H_;
  const short* WtK = WtHi + (size_t)(n * 3 + 0) * P_ * H_;
  const short* WtKl = WtLo + (size_t)(n * 3 + 0) * P_ * H_;
  const short* WtV = WtHi + (size_t)(n * 3 + 1) * P_ * H_;
  const short* WtVl = WtLo + (size_t)(n * 3 + 1) * P_ * H_;
  const short* WtQ = WtHi + (size_t)(n * 3 + 2) * P_ * H_;
  const short* WtQl = WtLo + (size_t)(n * 3 + 2) * P_ * H_;

  for (int k0 = 0; k0 < H_; k0 += 32) {
    // x frag (rows s, k-contig 8)
    f32x4 v0 = ld4f(xrow + k0 + 8 * q);
    f32x4 v1 = ld4f(xrow + k0 + 8 * q + 4);
    s16x8 xh, xl;
    #pragma unroll
    for (int e = 0; e < 4; ++e) {
      short hh = f2bf(v0[e]); xh[e] = hh; xl[e] = f2bf(v0[e] - bf2f(hh));
      short h2 = f2bf(v1[e]); xh[e + 4] = h2; xl[e + 4] = f2bf(v1[e] - bf2f(h2));
    }
    const size_t wko = (size_t)fr * H_ + k0 + 8 * q;
    #pragma unroll
    for (int pt = 0; pt < 4; ++pt) {
      size_t off = wko + (size_t)(16 * pt) * H_;
      accK[pt] = mm3(ld8(WtK + off), ld8(WtKl + off), xh, xl, accK[pt]);
    }
    #pragma unroll
    for (int pt = 0; pt < 4; ++pt) {
      size_t off = wko + (size_t)(16 * pt) * H_;
      accQ[pt] = mm3(ld8(WtQ + off), ld8(WtQl + off), xh, xl, accQ[pt]);
    }
    #pragma unroll
    for (int pt = 0; pt < 4; ++pt) {
      size_t off = wko + (size_t)(16 * pt) * H_;
      accV[pt] = mm3(xh, xl, ld8(WtV + off), ld8(WtVl + off), accV[pt]);
    }
  }

  // K/Q epilogue: lane holds s = s0+16w+fr, p = 16pt+4q+c
  #pragma unroll
  for (int pt = 0; pt < 4; ++pt) {
    s16x4 hK, lK, hQ, lQ;
    #pragma unroll
    for (int c = 0; c < 4; ++c) {
      float vk = accK[pt][c];
      short hh = f2bf(vk); hK[c] = hh; lK[c] = f2bf(vk - bf2f(hh));
      float vq = accQ[pt][c];
      short h2 = f2bf(vq); hQ[c] = h2; lQ[c] = f2bf(vq - bf2f(h2));
    }
    size_t off = ((size_t)bn * S_ + (s0 + 16 * w + fr)) * P_ + 16 * pt + 4 * q;
    *(s16x4*)(Khi + off) = hK;
    *(s16x4*)(Klo + off) = lK;
    *(s16x4*)(Qhi + off) = hQ;
    *(s16x4*)(Qlo + off) = lQ;
  }
  // V epilogue: lane holds s = s0+16w+4q+c, p = 16pt+fr -> VT[p][s] hi only
  #pragma unroll
  for (int pt = 0; pt < 4; ++pt) {
    s16x4 hV;
    #pragma unroll
    for (int c = 0; c < 4; ++c) hV[c] = f2bf(accV[pt][c]);
    size_t off = ((size_t)bn * P_ + (16 * pt + fr)) * S_ + s0 + 16 * w + 4 * q;
    *(s16x4*)(VThi + off) = hV;
  }
}

// ---------------------------------------------------------------------------
// Kernel 2: column stats, per-lane online softmax (no loop barriers).
// Block=(bn, j-tile 64), 4 waves = (jb in {0,32}) x (ih in {0,1}).
// ---------------------------------------------------------------------------
__global__ __launch_bounds__(256) void stats_kernel(
    const short* __restrict__ Khi, const short* __restrict__ Klo,
    const short* __restrict__ Qhi, const short* __restrict__ Qlo,
    float* __restrict__ cmax, float* __restrict__ csuminv)
{
  __shared__ float mbuf[2 * 64], zbuf[2 * 64];
  const int tid = threadIdx.x;
  const int bid = blockIdx.x;
  const int j0 = (bid & 31) * 64;
  const int bn = bid >> 5;
  const int w = tid >> 6, lane = tid & 63, q = lane >> 4, fr = lane & 15;
  const int jb = 32 * (w & 1), ih = w >> 1, ib0 = 32 * ih;

  // preload Q a-frags (fixed j-tile): rows j = j0+jb+16jt+fr, k = p
  s16x8 qh[2][2], ql[2][2];
  #pragma unroll
  for (int jt = 0; jt < 2; ++jt)
    #pragma unroll
    for (int ks = 0; ks < 2; ++ks) {
      size_t off = ((size_t)bn * S_ + (j0 + jb + 16 * jt + fr)) * P_ + 8 * q + 32 * ks;
      qh[jt][ks] = ld8(Qhi + off);
      ql[jt][ks] = ld8(Qlo + off);
    }

  f32x4 m[2], z[2];
  #pragma unroll
  for (int jt = 0; jt < 2; ++jt)
    #pragma unroll
    for (int c = 0; c < 4; ++c) { m[jt][c] = -3.0e38f; z[jt][c] = 0.0f; }

  for (int i0 = 0; i0 < S_; i0 += 64) {
    s16x8 kh[2][2], kl[2][2];
    #pragma unroll
    for (int it = 0; it < 2; ++it)
      #pragma unroll
      for (int ks = 0; ks < 2; ++ks) {
        size_t off = ((size_t)bn * S_ + (i0 + ib0 + 16 * it + fr)) * P_ + 8 * q + 32 * ks;
        kh[it][ks] = ld8(Khi + off);
        kl[it][ks] = ld8(Klo + off);
      }
    f32x4 sc[2][2] = {};
    #pragma unroll
    for (int ks = 0; ks < 2; ++ks)
      #pragma unroll
      for (int jt = 0; jt < 2; ++jt)
        #pragma unroll
        for (int it = 0; it < 2; ++it)
          sc[jt][it] = mm3(qh[jt][ks], ql[jt][ks], kh[it][ks], kl[it][ks], sc[jt][it]);

    #pragma unroll
    for (int jt = 0; jt < 2; ++jt) {
      f32x4 nm;
      #pragma unroll
      for (int c = 0; c < 4; ++c) {
        float s0v = sc[jt][0][c] * 0.125f, s1v = sc[jt][1][c] * 0.125f;
        sc[jt][0][c] = s0v; sc[jt][1][c] = s1v;
        nm[c] = fmaxf(m[jt][c], fmaxf(s0v, s1v));
      }
      #pragma unroll
      for (int c = 0; c < 4; ++c) {
        z[jt][c] = z[jt][c] * __expf(m[jt][c] - nm[c])
                 + __expf(sc[jt][0][c] - nm[c]) + __expf(sc[jt][1][c] - nm[c]);
        m[jt][c] = nm[c];
      }
    }
  }

  // reduce across the 16 fr-lanes (same j set)
  #pragma unroll
  for (int msk = 1; msk <= 8; msk <<= 1) {
    #pragma unroll
    for (int jt = 0; jt < 2; ++jt)
      #pragma unroll
      for (int c = 0; c < 4; ++c) {
        float om = __shfl_xor(m[jt][c], msk, 64);
        float oz = __shfl_xor(z[jt][c], msk, 64);
        float nm = fmaxf(m[jt][c], om);
        z[jt][c] = z[jt][c] * __expf(m[jt][c] - nm) + oz * __expf(om - nm);
        m[jt][c] = nm;
      }
  }
  if (fr == 0) {
    #pragma unroll
    for (int jt = 0; jt < 2; ++jt) {
      *(f32x4*)&mbuf[ih * 64 + jb + 16 * jt + 4 * q] = m[jt];
      *(f32x4*)&zbuf[ih * 64 + jb + 16 * jt + 4 * q] = z[jt];
    }
  }
  __syncthreads();
  if (tid < 64) {
    float m0 = mbuf[tid], m1 = mbuf[64 + tid];
    float nm = fmaxf(m0, m1);
    float zz = zbuf[tid] * __expf(m0 - nm) + zbuf[64 + tid] * __expf(m1 - nm);
    cmax[(size_t)bn * S_ + j0 + tid] = nm;
    csuminv[(size_t)bn * S_ + j0 + tid] = 1.0f / zz;
  }
}

// ---------------------------------------------------------------------------
// Kernel 3: AV pass. Block=(bn, i-tile 64), streams j. Double-buffered w-LDS
// (1 barrier/step). PV: w(hi+lo) x V(hi) = 2 mfma. hid written bf16 hi.
// ---------------------------------------------------------------------------
__global__ __launch_bounds__(256) void av_kernel(
    const short* __restrict__ Khi, const short* __restrict__ Klo,
    const short* __restrict__ Qhi, const short* __restrict__ Qlo,
    const short* __restrict__ VThi,
    const float* __restrict__ cmax, const float* __restrict__ csuminv,
    const int* __restrict__ mask, short* __restrict__ hidh)
{
  __shared__ short whi[2][64 * 64];
  __shared__ short wlo[2][64 * 64];
  const int tid = threadIdx.x;
  const int bid = blockIdx.x;
  const int i0 = (bid & 31) * 64;
  const int bn = bid >> 5;
  const int b = bn >> 4, n = bn & 15;
  const int w = tid >> 6, lane = tid & 63, q = lane >> 4, fr = lane & 15;
  const int jb = 32 * (w & 1), ih = w >> 1, ib = 32 * ih, pb = jb;
  const float INV_S = 1.0f / 2048.0f;

  // preload K b-frags (fixed i-tile)
  s16x8 kh[2][2], kl[2][2];
  #pragma unroll
  for (int it = 0; it < 2; ++it)
    #pragma unroll
    for (int ks = 0; ks < 2; ++ks) {
      size_t off = ((size_t)bn * S_ + (i0 + ib + 16 * it + fr)) * P_ + 8 * q + 32 * ks;
      kh[it][ks] = ld8(Khi + off);
      kl[it][ks] = ld8(Klo + off);
    }

  f32x4 opv[2][2] = {};

  for (int T = 0; T < S_ / 64; ++T) {
    const int j0 = T * 64;
    const int buf = T & 1;
    s16x8 aqh[2][2], aql[2][2];
    #pragma unroll
    for (int jt = 0; jt < 2; ++jt)
      #pragma unroll
      for (int ks = 0; ks < 2; ++ks) {
        size_t off = ((size_t)bn * S_ + (j0 + jb + 16 * jt + fr)) * P_ + 8 * q + 32 * ks;
        aqh[jt][ks] = ld8(Qhi + off);
        aql[jt][ks] = ld8(Qlo + off);
      }
    f32x4 sc[2][2] = {};
    #pragma unroll
    for (int ks = 0; ks < 2; ++ks)
      #pragma unroll
      for (int jt = 0; jt < 2; ++jt)
        #pragma unroll
        for (int it = 0; it < 2; ++it)
          sc[jt][it] = mm3(aqh[jt][ks], aql[jt][ks], kh[it][ks], kl[it][ks], sc[jt][it]);

    #pragma unroll
    for (int jt = 0; jt < 2; ++jt) {
      const int jq = j0 + jb + 16 * jt + 4 * q;
      f32x4 mj = ld4f(cmax + (size_t)bn * S_ + jq);
      f32x4 zj = ld4f(csuminv + (size_t)bn * S_ + jq);
      i32x4 mk = *(const i32x4*)(mask + (size_t)b * S_ + jq);
      #pragma unroll
      for (int it = 0; it < 2; ++it) {
        s16x4 h4, l4;
        #pragma unroll
        for (int c = 0; c < 4; ++c) {
          float s = sc[jt][it][c] * 0.125f;
          float wv = (mk[c] != 0) ? __expf(s - mj[c]) * zj[c] : INV_S;
          short hh = f2bf(wv);
          h4[c] = hh;
          l4[c] = f2bf(wv - bf2f(hh));
        }
        int irow = ib + 16 * it + fr;
        int addr = (irow * 128 + (jb + 16 * jt + 4 * q) * 2) ^ ((irow & 7) << 4);
        *(s16x4*)((char*)whi[buf] + addr) = h4;
        *(s16x4*)((char*)wlo[buf] + addr) = l4;
      }
    }
    __syncthreads();   // w ready; prior-step PV reads are older in program order

    #pragma unroll
    for (int ks2 = 0; ks2 < 2; ++ks2) {
      s16x8 vh[2], wh[2], wl2[2];
      #pragma unroll
      for (int pt = 0; pt < 2; ++pt) {
        size_t off = ((size_t)bn * P_ + (pb + 16 * pt + fr)) * S_ + j0 + 32 * ks2 + 8 * q;
        vh[pt] = ld8(VThi + off);
      }
      #pragma unroll
      for (int it = 0; it < 2; ++it) {
        int irow = ib + 16 * it + fr;
        int addr = (irow * 128 + 64 * ks2 + 16 * q) ^ ((irow & 7) << 4);
        wh[it]  = *(const s16x8*)((const char*)whi[buf] + addr);
        wl2[it] = *(const s16x8*)((const char*)wlo[buf] + addr);
      }
      #pragma unroll
      for (int pt = 0; pt < 2; ++pt)
        #pragma unroll
        for (int it = 0; it < 2; ++it) {
          opv[pt][it] = __builtin_amdgcn_mfma_f32_16x16x32_bf16(vh[pt], wh[it], opv[pt][it], 0, 0, 0);
          opv[pt][it] = __builtin_amdgcn_mfma_f32_16x16x32_bf16(vh[pt], wl2[it], opv[pt][it], 0, 0, 0);
        }
    }
  }

  #pragma unroll
  for (int pt = 0; pt < 2; ++pt)
    #pragma unroll
    for (int it = 0; it < 2; ++it) {
      int srow = i0 + ib + 16 * it + fr;
      int hcol = n * P_ + pb + 16 * pt + 4 * q;
      s16x4 hv;
      #pragma unroll
      for (int c = 0; c < 4; ++c) hv[c] = f2bf(opv[pt][it][c]);
      *(s16x4*)(hidh + ((size_t)b * S_ + srow) * H_ + hcol) = hv;
    }
}

// ---------------------------------------------------------------------------
// Kernel 4: out = hid @ Wl.T + bl via MFMA (Wl hi/lo x hid hi).
// Block=(rt, ot): 64 r x 64 o; 4 waves = r-subtiles.
// ---------------------------------------------------------------------------
__global__ __launch_bounds__(256) void final_kernel(
    const short* __restrict__ hidh,
    const short* __restrict__ WlHi, const short* __restrict__ WlLo,
    const float* __restrict__ bl, float* __restrict__ out)
{
  const int tid = threadIdx.x;
  const int ot = blockIdx.x & 15;
  const int rt = blockIdx.x >> 4;
  const int w = tid >> 6, lane = tid & 63, q = lane >> 4, fr = lane & 15;
  const int r = rt * 64 + 16 * w + fr;

  f32x4 acc[4] = {};
  const short* hrow = hidh + (size_t)r * H_;
  for (int k0 = 0; k0 < H_; k0 += 32) {
    s16x8 bh0 = ld8(hrow + k0 + 8 * q);
    #pragma unroll
    for (int oi = 0; oi < 4; ++oi) {
      size_t off = ((size_t)(ot * 64 + 16 * oi + fr)) * H_ + k0 + 8 * q;
      s16x8 ah = ld8(WlHi + off);
      s16x8 al = ld8(WlLo + off);
      acc[oi] = __builtin_amdgcn_mfma_f32_16x16x32_bf16(ah, bh0, acc[oi], 0, 0, 0);
      acc[oi] = __builtin_amdgcn_mfma_f32_16x16x32_bf16(al, bh0, acc[oi], 0, 0, 0);
    }
  }
  #pragma unroll
  for (int oi = 0; oi < 4; ++oi) {
    int o = ot * 64 + 16 * oi + 4 * q;
    f32x4 bv = ld4f(bl + o);
    f32x4 v;
    #pragma unroll
    for (int c = 0; c < 4; ++c) v[c] = acc[oi][c] + bv[c];
    *(f32x4*)(out + (size_t)r * H_ + o) = v;
  }
}

// ---------------------------------------------------------------------------
extern "C" void kernel_launch(void* const* d_in, const int* in_sizes, int n_in,
                              void* d_out, int out_size, void* d_ws, size_t ws_size,
                              hipStream_t stream) {
  const float* x    = (const float*)d_in[0];
  const int*   mask = (const int*)d_in[1];
  const float* W    = (const float*)d_in[2];
  const float* Wl   = (const float*)d_in[3];
  const float* bl   = (const float*)d_in[4];
  float* out = (float*)d_out;

  const size_t SZ  = (size_t)B_ * NH_ * S_ * P_;      // 4,194,304
  const size_t SZW = (size_t)NH_ * 3 * H_ * P_;       // 3,145,728
  const size_t SZL = (size_t)H_ * H_;                 // 1,048,576
  const size_t SZC = (size_t)B_ * NH_ * S_;           // 65,536

  char* p = (char*)d_ws;
  short* Khi  = (short*)p; p += SZ * 2;
  short* Klo  = (short*)p; p += SZ * 2;
  short* Qhi  = (short*)p; p += SZ * 2;
  short* Qlo  = (short*)p; p += SZ * 2;
  short* VThi = (short*)p; p += SZ * 2;
  short* WtHi = (short*)p; p += SZW * 2;
  short* WtLo = (short*)p; p += SZW * 2;
  short* WlHi = (short*)p; p += SZL * 2;
  short* WlLo = (short*)p; p += SZL * 2;
  float* cmax    = (float*)p; p += SZC * 4;
  float* csuminv = (float*)p; p += SZC * 4;
  short* hidh = WtHi;  // alias: Wt region (12.58 MB) free after qkv; hid = 8.39 MB
  // total distinct = 59.2 MB

  tw_kernel   <<<NH_ * 3 * (H_ / 64), 256, 0, stream>>>(W, WtHi, WtLo);
  swl_kernel  <<<(SZL / 4) / 256, 256, 0, stream>>>(Wl, WlHi, WlLo);
  qkv_kernel  <<<B_ * NH_ * (S_ / 64), 256, 0, stream>>>(
      x, WtHi, WtLo, Khi, Klo, Qhi, Qlo, VThi);
  stats_kernel<<<B_ * NH_ * (S_ / 64), 256, 0, stream>>>(
      Khi, Klo, Qhi, Qlo, cmax, csuminv);
  av_kernel   <<<B_ * NH_ * (S_ / 64), 256, 0, stream>>>(
      Khi, Klo, Qhi, Qlo, VThi, cmax, csuminv, mask, hidh);
  final_kernel<<<(B_ * S_ / 64) * (H_ / 64), 256, 0, stream>>>(
      hidh, WlHi, WlLo, bl, out);
}

// Round 5
// 540.291 us; speedup vs baseline: 25.9225x; 1.6895x over previous
//
#include <hip/hip_runtime.h>

// Problem constants (B,S,H,NH,P) = (2,2048,1024,16,64)
#define B_ 2
#define S_ 2048
#define H_ 1024
#define NH_ 16
#define P_ 64

using f32x4 = __attribute__((ext_vector_type(4))) float;
using i32x4 = __attribute__((ext_vector_type(4))) int;
using s16x8 = __attribute__((ext_vector_type(8))) short;
using s16x4 = __attribute__((ext_vector_type(4))) short;

static __device__ __forceinline__ short f2bf(float f) {
  unsigned u = __float_as_uint(f);
  unsigned r = (u + 0x7fffu + ((u >> 16) & 1u)) >> 16;
  return (short)r;
}
static __device__ __forceinline__ float bf2f(short s) {
  return __uint_as_float(((unsigned)(unsigned short)s) << 16);
}
static __device__ __forceinline__ s16x8 ld8(const short* p) { return *(const s16x8*)p; }
static __device__ __forceinline__ f32x4 ld4f(const float* p) { return *(const f32x4*)p; }

// bf16x3 fused: c += ahi*bhi + ahi*blo + alo*bhi
static __device__ __forceinline__ f32x4 mm3(s16x8 ah, s16x8 al, s16x8 bh, s16x8 bl, f32x4 c) {
  c = __builtin_amdgcn_mfma_f32_16x16x32_bf16(ah, bh, c, 0, 0, 0);
  c = __builtin_amdgcn_mfma_f32_16x16x32_bf16(ah, bl, c, 0, 0, 0);
  c = __builtin_amdgcn_mfma_f32_16x16x32_bf16(al, bh, c, 0, 0, 0);
  return c;
}

// ---------------------------------------------------------------------------
// Prep A: transpose+split W [NH][3][H][P] fp32 -> Wt hi/lo [NH][3][P][H] bf16
// ---------------------------------------------------------------------------
__global__ __launch_bounds__(256) void tw_kernel(
    const float* __restrict__ W, short* __restrict__ WtHi, short* __restrict__ WtLo)
{
  __shared__ float T[64 * 65];
  const int tid = threadIdx.x;
  const int nt = blockIdx.x >> 4;
  const int h0 = (blockIdx.x & 15) * 64;
  const float* src = W + (size_t)nt * H_ * P_ + (size_t)h0 * P_;
  #pragma unroll
  for (int r = 0; r < 4; ++r) {
    int idx = tid + r * 256;
    int h = idx >> 4, p4 = (idx & 15) << 2;
    f32x4 v = ld4f(src + (size_t)h * P_ + p4);
    #pragma unroll
    for (int i = 0; i < 4; ++i) T[(p4 + i) * 65 + h] = v[i];
  }
  __syncthreads();
  short* dh = WtHi + (size_t)nt * P_ * H_;
  short* dl = WtLo + (size_t)nt * P_ * H_;
  #pragma unroll
  for (int r = 0; r < 4; ++r) {
    int idx = tid + r * 256;
    int p = idx >> 4, h4 = (idx & 15) << 2;
    s16x4 hv, lv;
    #pragma unroll
    for (int i = 0; i < 4; ++i) {
      float f = T[p * 65 + h4 + i];
      short hh = f2bf(f);
      hv[i] = hh;
      lv[i] = f2bf(f - bf2f(hh));
    }
    *(s16x4*)(dh + (size_t)p * H_ + h0 + h4) = hv;
    *(s16x4*)(dl + (size_t)p * H_ + h0 + h4) = lv;
  }
}

// ---------------------------------------------------------------------------
// Prep B: split Wl [H][H] fp32 -> hi/lo bf16 (same layout).
// ---------------------------------------------------------------------------
__global__ __launch_bounds__(256) void swl_kernel(
    const float* __restrict__ Wl, short* __restrict__ WlHi, short* __restrict__ WlLo)
{
  int idx = blockIdx.x * 256 + threadIdx.x;
  f32x4 v = ((const f32x4*)Wl)[idx];
  s16x4 hv, lv;
  #pragma unroll
  for (int i = 0; i < 4; ++i) {
    short hh = f2bf(v[i]);
    hv[i] = hh;
    lv[i] = f2bf(v[i] - bf2f(hh));
  }
  ((s16x4*)WlHi)[idx] = hv;
  ((s16x4*)WlLo)[idx] = lv;
}

// ---------------------------------------------------------------------------
// Kernel 1: QKV via MFMA. x tile staged in LDS (bf16 hi/lo, double-buffered,
// 1 barrier/k-step). Wave w owns p-subtile 16w; Wt frags reused over 4
// s-subtiles. K,Q: D[p][s]=mfma(Wt,x) -> [bn][s][p] hi+lo. V: D[s][p]=
// mfma(x,Wt) -> VT[bn][p][s] hi only.
// ---------------------------------------------------------------------------
__global__ __launch_bounds__(256) void qkv_kernel(
    const float* __restrict__ x,
    const short* __restrict__ WtHi, const short* __restrict__ WtLo,
    short* __restrict__ Khi, short* __restrict__ Klo,
    short* __restrict__ Qhi, short* __restrict__ Qlo,
    short* __restrict__ VThi)
{
  __shared__ short xh_lds[2][64 * 32];
  __shared__ short xl_lds[2][64 * 32];

  int blk = blockIdx.x;
  const int st = blk & 31; blk >>= 5;
  const int n = blk & 15;
  const int b = blk >> 4;
  const int s0 = st * 64;
  const int tid = threadIdx.x;
  const int w = tid >> 6, lane = tid & 63, q = lane >> 4, fr = lane & 15;
  const int bn = b * NH_ + n;

  const int srow = tid >> 2, scc = tid & 3;           // staging: row, col-chunk
  const float* xsrc = x + ((size_t)b * S_ + s0 + srow) * H_ + 8 * scc;
  const int saddr = srow * 32 + ((scc ^ (srow & 3)) * 8);

  auto stage = [&](int k0, int bufsel) {
    f32x4 v0 = ld4f(xsrc + k0);
    f32x4 v1 = ld4f(xsrc + k0 + 4);
    s16x8 hv, lv;
    #pragma unroll
    for (int e = 0; e < 4; ++e) {
      short h0 = f2bf(v0[e]); hv[e] = h0; lv[e] = f2bf(v0[e] - bf2f(h0));
      short h1 = f2bf(v1[e]); hv[e + 4] = h1; lv[e + 4] = f2bf(v1[e] - bf2f(h1));
    }
    *(s16x8*)&xh_lds[bufsel][saddr] = hv;
    *(s16x8*)&xl_lds[bufsel][saddr] = lv;
  };

  const short* WtK  = WtHi + ((size_t)(n * 3 + 0) * P_ + 16 * w + fr) * H_ + 8 * q;
  const short* WtKl = WtLo + ((size_t)(n * 3 + 0) * P_ + 16 * w + fr) * H_ + 8 * q;
  const short* WtV  = WtHi + ((size_t)(n * 3 + 1) * P_ + 16 * w + fr) * H_ + 8 * q;
  const short* WtVl = WtLo + ((size_t)(n * 3 + 1) * P_ + 16 * w + fr) * H_ + 8 * q;
  const short* WtQ  = WtHi + ((size_t)(n * 3 + 2) * P_ + 16 * w + fr) * H_ + 8 * q;
  const short* WtQl = WtLo + ((size_t)(n * 3 + 2) * P_ + 16 * w + fr) * H_ + 8 * q;

  f32x4 accK[4] = {}, accQ[4] = {}, accV[4] = {};

  stage(0, 0);
  for (int step = 0; step < 32; ++step) {
    __syncthreads();
    if (step < 31) stage((step + 1) * 32, (step + 1) & 1);
    const int bs = step & 1;
    const int k0 = step * 32;

    s16x8 xh[4], xl[4];
    #pragma unroll
    for (int ss = 0; ss < 4; ++ss) {
      int addr = (16 * ss + fr) * 32 + ((q ^ (fr & 3)) * 8);
      xh[ss] = *(const s16x8*)&xh_lds[bs][addr];
      xl[ss] = *(const s16x8*)&xl_lds[bs][addr];
    }
    s16x8 wkh = ld8(WtK + k0),  wkl = ld8(WtKl + k0);
    s16x8 wqh = ld8(WtQ + k0),  wql = ld8(WtQl + k0);
    s16x8 wvh = ld8(WtV + k0),  wvl = ld8(WtVl + k0);
    #pragma unroll
    for (int ss = 0; ss < 4; ++ss) {
      accK[ss] = mm3(wkh, wkl, xh[ss], xl[ss], accK[ss]);
      accQ[ss] = mm3(wqh, wql, xh[ss], xl[ss], accQ[ss]);
      accV[ss] = mm3(xh[ss], xl[ss], wvh, wvl, accV[ss]);
    }
  }

  // K/Q epilogue: lane holds s = s0+16ss+fr, p = 16w+4q+c
  #pragma unroll
  for (int ss = 0; ss < 4; ++ss) {
    s16x4 hK, lK, hQ, lQ;
    #pragma unroll
    for (int c = 0; c < 4; ++c) {
      float vk = accK[ss][c];
      short hh = f2bf(vk); hK[c] = hh; lK[c] = f2bf(vk - bf2f(hh));
      float vq = accQ[ss][c];
      short h2 = f2bf(vq); hQ[c] = h2; lQ[c] = f2bf(vq - bf2f(h2));
    }
    size_t off = ((size_t)bn * S_ + (s0 + 16 * ss + fr)) * P_ + 16 * w + 4 * q;
    *(s16x4*)(Khi + off) = hK;
    *(s16x4*)(Klo + off) = lK;
    *(s16x4*)(Qhi + off) = hQ;
    *(s16x4*)(Qlo + off) = lQ;
  }
  // V epilogue: lane holds s = s0+16ss+4q+c, p = 16w+fr -> VT[p][s] hi only
  #pragma unroll
  for (int ss = 0; ss < 4; ++ss) {
    s16x4 hV;
    #pragma unroll
    for (int c = 0; c < 4; ++c) hV[c] = f2bf(accV[ss][c]);
    size_t off = ((size_t)bn * P_ + (16 * w + fr)) * S_ + s0 + 16 * ss + 4 * q;
    *(s16x4*)(VThi + off) = hV;
  }
}

// ---------------------------------------------------------------------------
// Kernel 2: column sum-exp (no max subtraction — scores ~N(0,1), safe).
// Block=(bn, j-tile 64), 4 waves = (jb) x (ih).
// ---------------------------------------------------------------------------
__global__ __launch_bounds__(256) void stats_kernel(
    const short* __restrict__ Khi, const short* __restrict__ Klo,
    const short* __restrict__ Qhi, const short* __restrict__ Qlo,
    float* __restrict__ csuminv)
{
  __shared__ float zbuf[2 * 64];
  const int tid = threadIdx.x;
  const int bid = blockIdx.x;
  const int j0 = (bid & 31) * 64;
  const int bn = bid >> 5;
  const int w = tid >> 6, lane = tid & 63, q = lane >> 4, fr = lane & 15;
  const int jb = 32 * (w & 1), ih = w >> 1, ib0 = 32 * ih;

  s16x8 qh[2][2], ql[2][2];
  #pragma unroll
  for (int jt = 0; jt < 2; ++jt)
    #pragma unroll
    for (int ks = 0; ks < 2; ++ks) {
      size_t off = ((size_t)bn * S_ + (j0 + jb + 16 * jt + fr)) * P_ + 8 * q + 32 * ks;
      qh[jt][ks] = ld8(Qhi + off);
      ql[jt][ks] = ld8(Qlo + off);
    }

  f32x4 z[2] = {};

  for (int i0 = 0; i0 < S_; i0 += 64) {
    s16x8 kh[2][2], kl[2][2];
    #pragma unroll
    for (int it = 0; it < 2; ++it)
      #pragma unroll
      for (int ks = 0; ks < 2; ++ks) {
        size_t off = ((size_t)bn * S_ + (i0 + ib0 + 16 * it + fr)) * P_ + 8 * q + 32 * ks;
        kh[it][ks] = ld8(Khi + off);
        kl[it][ks] = ld8(Klo + off);
      }
    f32x4 sc[2][2] = {};
    #pragma unroll
    for (int ks = 0; ks < 2; ++ks)
      #pragma unroll
      for (int jt = 0; jt < 2; ++jt)
        #pragma unroll
        for (int it = 0; it < 2; ++it)
          sc[jt][it] = mm3(qh[jt][ks], ql[jt][ks], kh[it][ks], kl[it][ks], sc[jt][it]);

    #pragma unroll
    for (int jt = 0; jt < 2; ++jt)
      #pragma unroll
      for (int c = 0; c < 4; ++c)
        z[jt][c] += __expf(sc[jt][0][c] * 0.125f) + __expf(sc[jt][1][c] * 0.125f);
  }

  #pragma unroll
  for (int msk = 1; msk <= 8; msk <<= 1)
    #pragma unroll
    for (int jt = 0; jt < 2; ++jt)
      #pragma unroll
      for (int c = 0; c < 4; ++c)
        z[jt][c] += __shfl_xor(z[jt][c], msk, 64);

  if (fr == 0) {
    #pragma unroll
    for (int jt = 0; jt < 2; ++jt)
      *(f32x4*)&zbuf[ih * 64 + jb + 16 * jt + 4 * q] = z[jt];
  }
  __syncthreads();
  if (tid < 64)
    csuminv[(size_t)bn * S_ + j0 + tid] = 1.0f / (zbuf[tid] + zbuf[64 + tid]);
}

// ---------------------------------------------------------------------------
// Kernel 3: AV pass. Block=(bn, i-tile 64), streams j. Double-buffered w-LDS.
// w = mk ? exp(s)*zinv : 1/S. hid written bf16 hi.
// ---------------------------------------------------------------------------
__global__ __launch_bounds__(256) void av_kernel(
    const short* __restrict__ Khi, const short* __restrict__ Klo,
    const short* __restrict__ Qhi, const short* __restrict__ Qlo,
    const short* __restrict__ VThi,
    const float* __restrict__ csuminv,
    const int* __restrict__ mask, short* __restrict__ hidh)
{
  __shared__ short whi[2][64 * 64];
  __shared__ short wlo[2][64 * 64];
  const int tid = threadIdx.x;
  const int bid = blockIdx.x;
  const int i0 = (bid & 31) * 64;
  const int bn = bid >> 5;
  const int b = bn >> 4, n = bn & 15;
  const int w = tid >> 6, lane = tid & 63, q = lane >> 4, fr = lane & 15;
  const int jb = 32 * (w & 1), ih = w >> 1, ib = 32 * ih, pb = jb;
  const float INV_S = 1.0f / 2048.0f;

  s16x8 kh[2][2], kl[2][2];
  #pragma unroll
  for (int it = 0; it < 2; ++it)
    #pragma unroll
    for (int ks = 0; ks < 2; ++ks) {
      size_t off = ((size_t)bn * S_ + (i0 + ib + 16 * it + fr)) * P_ + 8 * q + 32 * ks;
      kh[it][ks] = ld8(Khi + off);
      kl[it][ks] = ld8(Klo + off);
    }

  f32x4 opv[2][2] = {};

  for (int T = 0; T < S_ / 64; ++T) {
    const int j0 = T * 64;
    const int buf = T & 1;
    s16x8 aqh[2][2], aql[2][2];
    #pragma unroll
    for (int jt = 0; jt < 2; ++jt)
      #pragma unroll
      for (int ks = 0; ks < 2; ++ks) {
        size_t off = ((size_t)bn * S_ + (j0 + jb + 16 * jt + fr)) * P_ + 8 * q + 32 * ks;
        aqh[jt][ks] = ld8(Qhi + off);
        aql[jt][ks] = ld8(Qlo + off);
      }
    f32x4 sc[2][2] = {};
    #pragma unroll
    for (int ks = 0; ks < 2; ++ks)
      #pragma unroll
      for (int jt = 0; jt < 2; ++jt)
        #pragma unroll
        for (int it = 0; it < 2; ++it)
          sc[jt][it] = mm3(aqh[jt][ks], aql[jt][ks], kh[it][ks], kl[it][ks], sc[jt][it]);

    #pragma unroll
    for (int jt = 0; jt < 2; ++jt) {
      const int jq = j0 + jb + 16 * jt + 4 * q;
      f32x4 zj = ld4f(csuminv + (size_t)bn * S_ + jq);
      i32x4 mk = *(const i32x4*)(mask + (size_t)b * S_ + jq);
      #pragma unroll
      for (int it = 0; it < 2; ++it) {
        s16x4 h4, l4;
        #pragma unroll
        for (int c = 0; c < 4; ++c) {
          float s = sc[jt][it][c] * 0.125f;
          float wv = (mk[c] != 0) ? __expf(s) * zj[c] : INV_S;
          short hh = f2bf(wv);
          h4[c] = hh;
          l4[c] = f2bf(wv - bf2f(hh));
        }
        int irow = ib + 16 * it + fr;
        int addr = (irow * 128 + (jb + 16 * jt + 4 * q) * 2) ^ ((irow & 7) << 4);
        *(s16x4*)((char*)whi[buf] + addr) = h4;
        *(s16x4*)((char*)wlo[buf] + addr) = l4;
      }
    }
    __syncthreads();

    #pragma unroll
    for (int ks2 = 0; ks2 < 2; ++ks2) {
      s16x8 vh[2], wh[2], wl2[2];
      #pragma unroll
      for (int pt = 0; pt < 2; ++pt) {
        size_t off = ((size_t)bn * P_ + (pb + 16 * pt + fr)) * S_ + j0 + 32 * ks2 + 8 * q;
        vh[pt] = ld8(VThi + off);
      }
      #pragma unroll
      for (int it = 0; it < 2; ++it) {
        int irow = ib + 16 * it + fr;
        int addr = (irow * 128 + 64 * ks2 + 16 * q) ^ ((irow & 7) << 4);
        wh[it]  = *(const s16x8*)((const char*)whi[buf] + addr);
        wl2[it] = *(const s16x8*)((const char*)wlo[buf] + addr);
      }
      #pragma unroll
      for (int pt = 0; pt < 2; ++pt)
        #pragma unroll
        for (int it = 0; it < 2; ++it) {
          opv[pt][it] = __builtin_amdgcn_mfma_f32_16x16x32_bf16(vh[pt], wh[it], opv[pt][it], 0, 0, 0);
          opv[pt][it] = __builtin_amdgcn_mfma_f32_16x16x32_bf16(vh[pt], wl2[it], opv[pt][it], 0, 0, 0);
        }
    }
  }

  #pragma unroll
  for (int pt = 0; pt < 2; ++pt)
    #pragma unroll
    for (int it = 0; it < 2; ++it) {
      int srow = i0 + ib + 16 * it + fr;
      int hcol = n * P_ + pb + 16 * pt + 4 * q;
      s16x4 hv;
      #pragma unroll
      for (int c = 0; c < 4; ++c) hv[c] = f2bf(opv[pt][it][c]);
      *(s16x4*)(hidh + ((size_t)b * S_ + srow) * H_ + hcol) = hv;
    }
}

// ---------------------------------------------------------------------------
// Kernel 4: out = hid @ Wl.T + bl via MFMA. hid tile staged in LDS (already
// bf16), double-buffered. Wave w owns o-subtile 16w; Wl frags reused 4x.
// D[o][r] = mfma(Wl, hid).
// ---------------------------------------------------------------------------
__global__ __launch_bounds__(256) void final_kernel(
    const short* __restrict__ hidh,
    const short* __restrict__ WlHi, const short* __restrict__ WlLo,
    const float* __restrict__ bl, float* __restrict__ out)
{
  __shared__ short hl[2][64 * 32];
  const int tid = threadIdx.x;
  const int ot = blockIdx.x & 15;
  const int rt = blockIdx.x >> 4;
  const int r0 = rt * 64, o0 = ot * 64;
  const int w = tid >> 6, lane = tid & 63, q = lane >> 4, fr = lane & 15;

  const int srow = tid >> 2, scc = tid & 3;
  const short* hsrc = hidh + (size_t)(r0 + srow) * H_ + 8 * scc;
  const int saddr = srow * 32 + ((scc ^ (srow & 3)) * 8);

  auto stage = [&](int k0, int bufsel) {
    *(s16x8*)&hl[bufsel][saddr] = ld8(hsrc + k0);
  };

  const short* WlA  = WlHi + ((size_t)(o0 + 16 * w + fr)) * H_ + 8 * q;
  const short* WlAl = WlLo + ((size_t)(o0 + 16 * w + fr)) * H_ + 8 * q;

  f32x4 acc[4] = {};

  stage(0, 0);
  for (int step = 0; step < 32; ++step) {
    __syncthreads();
    if (step < 31) stage((step + 1) * 32, (step + 1) & 1);
    const int bs = step & 1;
    const int k0 = step * 32;

    s16x8 bh[4];
    #pragma unroll
    for (int ss = 0; ss < 4; ++ss) {
      int addr = (16 * ss + fr) * 32 + ((q ^ (fr & 3)) * 8);
      bh[ss] = *(const s16x8*)&hl[bs][addr];
    }
    s16x8 ah = ld8(WlA + k0);
    s16x8 al = ld8(WlAl + k0);
    #pragma unroll
    for (int ss = 0; ss < 4; ++ss) {
      acc[ss] = __builtin_amdgcn_mfma_f32_16x16x32_bf16(ah, bh[ss], acc[ss], 0, 0, 0);
      acc[ss] = __builtin_amdgcn_mfma_f32_16x16x32_bf16(al, bh[ss], acc[ss], 0, 0, 0);
    }
  }

  // lane holds o = o0+16w+4q+c, r = r0+16ss+fr
  const int o = o0 + 16 * w + 4 * q;
  f32x4 bv = ld4f(bl + o);
  #pragma unroll
  for (int ss = 0; ss < 4; ++ss) {
    f32x4 v;
    #pragma unroll
    for (int c = 0; c < 4; ++c) v[c] = acc[ss][c] + bv[c];
    *(f32x4*)(out + (size_t)(r0 + 16 * ss + fr) * H_ + o) = v;
  }
}

// ---------------------------------------------------------------------------
extern "C" void kernel_launch(void* const* d_in, const int* in_sizes, int n_in,
                              void* d_out, int out_size, void* d_ws, size_t ws_size,
                              hipStream_t stream) {
  const float* x    = (const float*)d_in[0];
  const int*   mask = (const int*)d_in[1];
  const float* W    = (const float*)d_in[2];
  const float* Wl   = (const float*)d_in[3];
  const float* bl   = (const float*)d_in[4];
  float* out = (float*)d_out;

  const size_t SZ  = (size_t)B_ * NH_ * S_ * P_;      // 4,194,304
  const size_t SZW = (size_t)NH_ * 3 * H_ * P_;       // 3,145,728
  const size_t SZL = (size_t)H_ * H_;                 // 1,048,576
  const size_t SZC = (size_t)B_ * NH_ * S_;           // 65,536

  char* p = (char*)d_ws;
  short* Khi  = (short*)p; p += SZ * 2;
  short* Klo  = (short*)p; p += SZ * 2;
  short* Qhi  = (short*)p; p += SZ * 2;
  short* Qlo  = (short*)p; p += SZ * 2;
  short* VThi = (short*)p; p += SZ * 2;
  short* WtHi = (short*)p; p += SZW * 2;
  short* WtLo = (short*)p; p += SZW * 2;
  short* WlHi = (short*)p; p += SZL * 2;
  short* WlLo = (short*)p; p += SZL * 2;
  float* csuminv = (float*)p; p += SZC * 4;
  short* hidh = WtHi;  // alias: Wt region free after qkv

  tw_kernel   <<<NH_ * 3 * (H_ / 64), 256, 0, stream>>>(W, WtHi, WtLo);
  swl_kernel  <<<(SZL / 4) / 256, 256, 0, stream>>>(Wl, WlHi, WlLo);
  qkv_kernel  <<<B_ * NH_ * (S_ / 64), 256, 0, stream>>>(
      x, WtHi, WtLo, Khi, Klo, Qhi, Qlo, VThi);
  stats_kernel<<<B_ * NH_ * (S_ / 64), 256, 0, stream>>>(
      Khi, Klo, Qhi, Qlo, csuminv);
  av_kernel   <<<B_ * NH_ * (S_ / 64), 256, 0, stream>>>(
      Khi, Klo, Qhi, Qlo, VThi, csuminv, mask, hidh);
  final_kernel<<<(B_ * S_ / 64) * (H_ / 64), 256, 0, stream>>>(
      hidh, WlHi, WlLo, bl, out);
}

// Round 6
// 448.009 us; speedup vs baseline: 31.2620x; 1.2060x over previous
//
#include <hip/hip_runtime.h>

// Problem constants (B,S,H,NH,P) = (2,2048,1024,16,64)
#define B_ 2
#define S_ 2048
#define H_ 1024
#define NH_ 16
#define P_ 64

using f32x4 = __attribute__((ext_vector_type(4))) float;
using i32x4 = __attribute__((ext_vector_type(4))) int;
using s16x8 = __attribute__((ext_vector_type(8))) short;
using s16x4 = __attribute__((ext_vector_type(4))) short;
using f16   = _Float16;
using f16x8 = __attribute__((ext_vector_type(8))) f16;
using f16x4 = __attribute__((ext_vector_type(4))) f16;

static __device__ __forceinline__ short f2bf(float f) {
  unsigned u = __float_as_uint(f);
  unsigned r = (u + 0x7fffu + ((u >> 16) & 1u)) >> 16;
  return (short)r;
}
static __device__ __forceinline__ float bf2f(short s) {
  return __uint_as_float(((unsigned)(unsigned short)s) << 16);
}
static __device__ __forceinline__ s16x8 ld8(const short* p) { return *(const s16x8*)p; }
static __device__ __forceinline__ f16x8 ldh8(const f16* p) { return *(const f16x8*)p; }
static __device__ __forceinline__ f32x4 ld4f(const float* p) { return *(const f32x4*)p; }

// bf16x3 fused: c += ahi*bhi + ahi*blo + alo*bhi  (qkv projection accuracy)
static __device__ __forceinline__ f32x4 mm3(s16x8 ah, s16x8 al, s16x8 bh, s16x8 bl, f32x4 c) {
  c = __builtin_amdgcn_mfma_f32_16x16x32_bf16(ah, bh, c, 0, 0, 0);
  c = __builtin_amdgcn_mfma_f32_16x16x32_bf16(ah, bl, c, 0, 0, 0);
  c = __builtin_amdgcn_mfma_f32_16x16x32_bf16(al, bh, c, 0, 0, 0);
  return c;
}
static __device__ __forceinline__ f32x4 mm16(f16x8 a, f16x8 b, f32x4 c) {
  return __builtin_amdgcn_mfma_f32_16x16x32_f16(a, b, c, 0, 0, 0);
}

// ---------------------------------------------------------------------------
// Prep A: transpose+split W [NH][3][H][P] fp32 -> Wt hi/lo [NH][3][P][H] bf16
// ---------------------------------------------------------------------------
__global__ __launch_bounds__(256) void tw_kernel(
    const float* __restrict__ W, short* __restrict__ WtHi, short* __restrict__ WtLo)
{
  __shared__ float T[64 * 65];
  const int tid = threadIdx.x;
  const int nt = blockIdx.x >> 4;
  const int h0 = (blockIdx.x & 15) * 64;
  const float* src = W + (size_t)nt * H_ * P_ + (size_t)h0 * P_;
  #pragma unroll
  for (int r = 0; r < 4; ++r) {
    int idx = tid + r * 256;
    int h = idx >> 4, p4 = (idx & 15) << 2;
    f32x4 v = ld4f(src + (size_t)h * P_ + p4);
    #pragma unroll
    for (int i = 0; i < 4; ++i) T[(p4 + i) * 65 + h] = v[i];
  }
  __syncthreads();
  short* dh = WtHi + (size_t)nt * P_ * H_;
  short* dl = WtLo + (size_t)nt * P_ * H_;
  #pragma unroll
  for (int r = 0; r < 4; ++r) {
    int idx = tid + r * 256;
    int p = idx >> 4, h4 = (idx & 15) << 2;
    s16x4 hv, lv;
    #pragma unroll
    for (int i = 0; i < 4; ++i) {
      float f = T[p * 65 + h4 + i];
      short hh = f2bf(f);
      hv[i] = hh;
      lv[i] = f2bf(f - bf2f(hh));
    }
    *(s16x4*)(dh + (size_t)p * H_ + h0 + h4) = hv;
    *(s16x4*)(dl + (size_t)p * H_ + h0 + h4) = lv;
  }
}

// ---------------------------------------------------------------------------
// Prep B: convert Wl [H][H] fp32 -> fp16
// ---------------------------------------------------------------------------
__global__ __launch_bounds__(256) void swl_kernel(
    const float* __restrict__ Wl, f16* __restrict__ WlH)
{
  int idx = blockIdx.x * 256 + threadIdx.x;
  f32x4 v = ((const f32x4*)Wl)[idx];
  f16x4 h;
  #pragma unroll
  for (int i = 0; i < 4; ++i) h[i] = (f16)v[i];
  ((f16x4*)WlH)[idx] = h;
}

// ---------------------------------------------------------------------------
// Kernel 1: QKV via MFMA bf16x3 (accurate); outputs stored single fp16.
// K,Q -> [bn][s][p]; V -> VT[bn][p][s].
// ---------------------------------------------------------------------------
__global__ __launch_bounds__(256) void qkv_kernel(
    const float* __restrict__ x,
    const short* __restrict__ WtHi, const short* __restrict__ WtLo,
    f16* __restrict__ Kh, f16* __restrict__ Qh, f16* __restrict__ VTh)
{
  __shared__ short xh_lds[2][64 * 32];
  __shared__ short xl_lds[2][64 * 32];

  int blk = blockIdx.x;
  const int st = blk & 31; blk >>= 5;
  const int n = blk & 15;
  const int b = blk >> 4;
  const int s0 = st * 64;
  const int tid = threadIdx.x;
  const int w = tid >> 6, lane = tid & 63, q = lane >> 4, fr = lane & 15;
  const int bn = b * NH_ + n;

  const int srow = tid >> 2, scc = tid & 3;
  const float* xsrc = x + ((size_t)b * S_ + s0 + srow) * H_ + 8 * scc;
  const int saddr = srow * 32 + ((scc ^ (srow & 3)) * 8);

  auto stage = [&](int k0, int bufsel) {
    f32x4 v0 = ld4f(xsrc + k0);
    f32x4 v1 = ld4f(xsrc + k0 + 4);
    s16x8 hv, lv;
    #pragma unroll
    for (int e = 0; e < 4; ++e) {
      short h0 = f2bf(v0[e]); hv[e] = h0; lv[e] = f2bf(v0[e] - bf2f(h0));
      short h1 = f2bf(v1[e]); hv[e + 4] = h1; lv[e + 4] = f2bf(v1[e] - bf2f(h1));
    }
    *(s16x8*)&xh_lds[bufsel][saddr] = hv;
    *(s16x8*)&xl_lds[bufsel][saddr] = lv;
  };

  const short* WtK  = WtHi + ((size_t)(n * 3 + 0) * P_ + 16 * w + fr) * H_ + 8 * q;
  const short* WtKl = WtLo + ((size_t)(n * 3 + 0) * P_ + 16 * w + fr) * H_ + 8 * q;
  const short* WtV  = WtHi + ((size_t)(n * 3 + 1) * P_ + 16 * w + fr) * H_ + 8 * q;
  const short* WtVl = WtLo + ((size_t)(n * 3 + 1) * P_ + 16 * w + fr) * H_ + 8 * q;
  const short* WtQ  = WtHi + ((size_t)(n * 3 + 2) * P_ + 16 * w + fr) * H_ + 8 * q;
  const short* WtQl = WtLo + ((size_t)(n * 3 + 2) * P_ + 16 * w + fr) * H_ + 8 * q;

  f32x4 accK[4] = {}, accQ[4] = {}, accV[4] = {};

  stage(0, 0);
  for (int step = 0; step < 32; ++step) {
    __syncthreads();
    if (step < 31) stage((step + 1) * 32, (step + 1) & 1);
    const int bs = step & 1;
    const int k0 = step * 32;

    s16x8 xh[4], xl[4];
    #pragma unroll
    for (int ss = 0; ss < 4; ++ss) {
      int addr = (16 * ss + fr) * 32 + ((q ^ (fr & 3)) * 8);
      xh[ss] = *(const s16x8*)&xh_lds[bs][addr];
      xl[ss] = *(const s16x8*)&xl_lds[bs][addr];
    }
    s16x8 wkh = ld8(WtK + k0),  wkl = ld8(WtKl + k0);
    s16x8 wqh = ld8(WtQ + k0),  wql = ld8(WtQl + k0);
    s16x8 wvh = ld8(WtV + k0),  wvl = ld8(WtVl + k0);
    #pragma unroll
    for (int ss = 0; ss < 4; ++ss) {
      accK[ss] = mm3(wkh, wkl, xh[ss], xl[ss], accK[ss]);
      accQ[ss] = mm3(wqh, wql, xh[ss], xl[ss], accQ[ss]);
      accV[ss] = mm3(xh[ss], xl[ss], wvh, wvl, accV[ss]);
    }
  }

  // K/Q epilogue: lane holds s = s0+16ss+fr, p = 16w+4q+c
  #pragma unroll
  for (int ss = 0; ss < 4; ++ss) {
    f16x4 hK, hQ;
    #pragma unroll
    for (int c = 0; c < 4; ++c) {
      hK[c] = (f16)accK[ss][c];
      hQ[c] = (f16)accQ[ss][c];
    }
    size_t off = ((size_t)bn * S_ + (s0 + 16 * ss + fr)) * P_ + 16 * w + 4 * q;
    *(f16x4*)(Kh + off) = hK;
    *(f16x4*)(Qh + off) = hQ;
  }
  // V epilogue: lane holds s = s0+16ss+4q+c, p = 16w+fr -> VT[p][s]
  #pragma unroll
  for (int ss = 0; ss < 4; ++ss) {
    f16x4 hV;
    #pragma unroll
    for (int c = 0; c < 4; ++c) hV[c] = (f16)accV[ss][c];
    size_t off = ((size_t)bn * P_ + (16 * w + fr)) * S_ + s0 + 16 * ss + 4 * q;
    *(f16x4*)(VTh + off) = hV;
  }
}

// ---------------------------------------------------------------------------
// Kernel 2: column sum-exp. Per-lane accumulation, no loop barriers.
// ---------------------------------------------------------------------------
__global__ __launch_bounds__(256) void stats_kernel(
    const f16* __restrict__ Kh, const f16* __restrict__ Qh,
    float* __restrict__ csuminv)
{
  __shared__ float zbuf[2 * 64];
  const int tid = threadIdx.x;
  const int bid = blockIdx.x;
  const int j0 = (bid & 31) * 64;
  const int bn = bid >> 5;
  const int w = tid >> 6, lane = tid & 63, q = lane >> 4, fr = lane & 15;
  const int jb = 32 * (w & 1), ih = w >> 1, ib0 = 32 * ih;

  f16x8 qf[2][2];
  #pragma unroll
  for (int jt = 0; jt < 2; ++jt)
    #pragma unroll
    for (int ks = 0; ks < 2; ++ks)
      qf[jt][ks] = ldh8(Qh + ((size_t)bn * S_ + (j0 + jb + 16 * jt + fr)) * P_ + 8 * q + 32 * ks);

  f32x4 z[2] = {};

  for (int i0 = 0; i0 < S_; i0 += 64) {
    f16x8 kf[2][2];
    #pragma unroll
    for (int it = 0; it < 2; ++it)
      #pragma unroll
      for (int ks = 0; ks < 2; ++ks)
        kf[it][ks] = ldh8(Kh + ((size_t)bn * S_ + (i0 + ib0 + 16 * it + fr)) * P_ + 8 * q + 32 * ks);
    f32x4 sc[2][2] = {};
    #pragma unroll
    for (int ks = 0; ks < 2; ++ks)
      #pragma unroll
      for (int jt = 0; jt < 2; ++jt)
        #pragma unroll
        for (int it = 0; it < 2; ++it)
          sc[jt][it] = mm16(qf[jt][ks], kf[it][ks], sc[jt][it]);

    #pragma unroll
    for (int jt = 0; jt < 2; ++jt)
      #pragma unroll
      for (int c = 0; c < 4; ++c)
        z[jt][c] += __expf(sc[jt][0][c] * 0.125f) + __expf(sc[jt][1][c] * 0.125f);
  }

  #pragma unroll
  for (int msk = 1; msk <= 8; msk <<= 1)
    #pragma unroll
    for (int jt = 0; jt < 2; ++jt)
      #pragma unroll
      for (int c = 0; c < 4; ++c)
        z[jt][c] += __shfl_xor(z[jt][c], msk, 64);

  if (fr == 0) {
    #pragma unroll
    for (int jt = 0; jt < 2; ++jt)
      *(f32x4*)&zbuf[ih * 64 + jb + 16 * jt + 4 * q] = z[jt];
  }
  __syncthreads();
  if (tid < 64)
    csuminv[(size_t)bn * S_ + j0 + tid] = 1.0f / (zbuf[tid] + zbuf[64 + tid]);
}

// ---------------------------------------------------------------------------
// Kernel 2.5: V' = mask ? zinv*V : 0 (in-place on VT); C[bn][p] = (1/S)*sum
// of masked-out V. grid = B*NH*16 blocks; wave per p-row.
// ---------------------------------------------------------------------------
__global__ __launch_bounds__(256) void scale_kernel(
    f16* __restrict__ VT, const float* __restrict__ csuminv,
    const int* __restrict__ mask, float* __restrict__ Cbuf)
{
  const int bid = blockIdx.x;
  const int bn = bid >> 4;
  const int b = bn >> 4;
  const int p = (bid & 15) * 4 + (threadIdx.x >> 6);
  const int lane = threadIdx.x & 63;
  f16* row = VT + ((size_t)bn * P_ + p) * S_;
  const float* zr = csuminv + (size_t)bn * S_;
  const int* mr = mask + (size_t)b * S_;
  float acc = 0.0f;
  #pragma unroll
  for (int k = 0; k < 4; ++k) {
    int s = (lane + 64 * k) * 8;
    f16x8 v = *(const f16x8*)(row + s);
    f32x4 z0 = ld4f(zr + s), z1 = ld4f(zr + s + 4);
    i32x4 m0 = *(const i32x4*)(mr + s), m1 = *(const i32x4*)(mr + s + 4);
    f16x8 o;
    #pragma unroll
    for (int e = 0; e < 4; ++e) {
      float fv = (float)v[e];
      if (m0[e] != 0) o[e] = (f16)(fv * z0[e]);
      else { o[e] = (f16)0.0f; acc += fv; }
      float fv2 = (float)v[e + 4];
      if (m1[e] != 0) o[e + 4] = (f16)(fv2 * z1[e]);
      else { o[e + 4] = (f16)0.0f; acc += fv2; }
    }
    *(f16x8*)(row + s) = o;
  }
  #pragma unroll
  for (int msk = 1; msk <= 32; msk <<= 1) acc += __shfl_xor(acc, msk, 64);
  if (lane == 0) Cbuf[bn * P_ + p] = acc * (1.0f / S_);
}

// ---------------------------------------------------------------------------
// Kernel 3: AV pass. Block=(bn, i-tile 32), grid 2048, streams j (step 64).
// out[i] = sum_j exp(s_ij)*V'[j] + C.  hid written fp16.
// ---------------------------------------------------------------------------
__global__ __launch_bounds__(256) void av_kernel(
    const f16* __restrict__ Kh, const f16* __restrict__ Qh,
    const f16* __restrict__ VT, const float* __restrict__ Cbuf,
    f16* __restrict__ hidh)
{
  __shared__ f16 wlds[2][32 * 64];
  const int tid = threadIdx.x;
  const int bid = blockIdx.x;
  const int i0 = (bid & 63) * 32;
  const int bn = bid >> 6;
  const int b = bn >> 4, n = bn & 15;
  const int w = tid >> 6, lane = tid & 63, q = lane >> 4, fr = lane & 15;
  const int jb = 32 * (w & 1), ib = 16 * (w >> 1), pb = jb;
  const int irow = ib + fr;

  // K b-frags for rows i0+ib+fr
  f16x8 kf[2];
  #pragma unroll
  for (int ks = 0; ks < 2; ++ks)
    kf[ks] = ldh8(Kh + ((size_t)bn * S_ + (i0 + irow)) * P_ + 8 * q + 32 * ks);

  f32x4 opv[2] = {};

  for (int T = 0; T < S_ / 64; ++T) {
    const int j0 = T * 64;
    const int buf = T & 1;
    f16x8 aq[2][2];
    #pragma unroll
    for (int jt = 0; jt < 2; ++jt)
      #pragma unroll
      for (int ks = 0; ks < 2; ++ks)
        aq[jt][ks] = ldh8(Qh + ((size_t)bn * S_ + (j0 + jb + 16 * jt + fr)) * P_ + 8 * q + 32 * ks);

    f32x4 sc[2] = {};
    #pragma unroll
    for (int ks = 0; ks < 2; ++ks)
      #pragma unroll
      for (int jt = 0; jt < 2; ++jt)
        sc[jt] = mm16(aq[jt][ks], kf[ks], sc[jt]);

    #pragma unroll
    for (int jt = 0; jt < 2; ++jt) {
      f16x4 h4;
      #pragma unroll
      for (int c = 0; c < 4; ++c) h4[c] = (f16)__expf(sc[jt][c] * 0.125f);
      int addr = (irow * 128 + (jb + 16 * jt + 4 * q) * 2) ^ ((irow & 7) << 4);
      *(f16x4*)((char*)wlds[buf] + addr) = h4;
    }
    __syncthreads();

    #pragma unroll
    for (int ks2 = 0; ks2 < 2; ++ks2) {
      f16x8 va[2];
      #pragma unroll
      for (int pt = 0; pt < 2; ++pt)
        va[pt] = ldh8(VT + ((size_t)bn * P_ + (pb + 16 * pt + fr)) * S_ + j0 + 32 * ks2 + 8 * q);
      int addr = (irow * 128 + (32 * ks2 + 8 * q) * 2) ^ ((irow & 7) << 4);
      f16x8 wf = *(const f16x8*)((const char*)wlds[buf] + addr);
      #pragma unroll
      for (int pt = 0; pt < 2; ++pt)
        opv[pt] = mm16(va[pt], wf, opv[pt]);
    }
  }

  // epilogue: lane holds p = pb+16pt+4q+c, i = i0+ib+fr
  #pragma unroll
  for (int pt = 0; pt < 2; ++pt) {
    const int pcol = pb + 16 * pt + 4 * q;
    f32x4 cv = ld4f(Cbuf + bn * P_ + pcol);
    f16x4 hv;
    #pragma unroll
    for (int c = 0; c < 4; ++c) hv[c] = (f16)(opv[pt][c] + cv[c]);
    *(f16x4*)(hidh + ((size_t)b * S_ + (i0 + irow)) * H_ + n * P_ + pcol) = hv;
  }
}

// ---------------------------------------------------------------------------
// Kernel 4: out = hid @ Wl.T + bl via fp16 MFMA. hid tile staged in LDS.
// ---------------------------------------------------------------------------
__global__ __launch_bounds__(256) void final_kernel(
    const f16* __restrict__ hidh, const f16* __restrict__ WlH,
    const float* __restrict__ bl, float* __restrict__ out)
{
  __shared__ f16 hl[2][64 * 32];
  const int tid = threadIdx.x;
  const int ot = blockIdx.x & 15;
  const int rt = blockIdx.x >> 4;
  const int r0 = rt * 64, o0 = ot * 64;
  const int w = tid >> 6, lane = tid & 63, q = lane >> 4, fr = lane & 15;

  const int srow = tid >> 2, scc = tid & 3;
  const f16* hsrc = hidh + (size_t)(r0 + srow) * H_ + 8 * scc;
  const int saddr = srow * 32 + ((scc ^ (srow & 3)) * 8);

  auto stage = [&](int k0, int bufsel) {
    *(f16x8*)&hl[bufsel][saddr] = ldh8(hsrc + k0);
  };

  const f16* WlA = WlH + ((size_t)(o0 + 16 * w + fr)) * H_ + 8 * q;

  f32x4 acc[4] = {};

  stage(0, 0);
  for (int step = 0; step < 32; ++step) {
    __syncthreads();
    if (step < 31) stage((step + 1) * 32, (step + 1) & 1);
    const int bs = step & 1;
    const int k0 = step * 32;

    f16x8 bh[4];
    #pragma unroll
    for (int ss = 0; ss < 4; ++ss) {
      int addr = (16 * ss + fr) * 32 + ((q ^ (fr & 3)) * 8);
      bh[ss] = *(const f16x8*)&hl[bs][addr];
    }
    f16x8 ah = ldh8(WlA + k0);
    #pragma unroll
    for (int ss = 0; ss < 4; ++ss)
      acc[ss] = mm16(ah, bh[ss], acc[ss]);
  }

  const int o = o0 + 16 * w + 4 * q;
  f32x4 bv = ld4f(bl + o);
  #pragma unroll
  for (int ss = 0; ss < 4; ++ss) {
    f32x4 v;
    #pragma unroll
    for (int c = 0; c < 4; ++c) v[c] = acc[ss][c] + bv[c];
    *(f32x4*)(out + (size_t)(r0 + 16 * ss + fr) * H_ + o) = v;
  }
}

// ---------------------------------------------------------------------------
extern "C" void kernel_launch(void* const* d_in, const int* in_sizes, int n_in,
                              void* d_out, int out_size, void* d_ws, size_t ws_size,
                              hipStream_t stream) {
  const float* x    = (const float*)d_in[0];
  const int*   mask = (const int*)d_in[1];
  const float* W    = (const float*)d_in[2];
  const float* Wl   = (const float*)d_in[3];
  const float* bl   = (const float*)d_in[4];
  float* out = (float*)d_out;

  const size_t SZ  = (size_t)B_ * NH_ * S_ * P_;      // 4,194,304
  const size_t SZW = (size_t)NH_ * 3 * H_ * P_;       // 3,145,728
  const size_t SZL = (size_t)H_ * H_;                 // 1,048,576
  const size_t SZC = (size_t)B_ * NH_ * S_;           // 65,536

  char* p = (char*)d_ws;
  f16*   Kh   = (f16*)p;  p += SZ * 2;
  f16*   Qh   = (f16*)p;  p += SZ * 2;
  f16*   VTh  = (f16*)p;  p += SZ * 2;
  short* WtHi = (short*)p; p += SZW * 2;
  short* WtLo = (short*)p; p += SZW * 2;
  f16*   WlH  = (f16*)p;  p += SZL * 2;
  float* csuminv = (float*)p; p += SZC * 4;
  float* Cbuf    = (float*)p; p += (size_t)B_ * NH_ * P_ * 4;
  f16* hidh = (f16*)WtHi;  // alias: Wt region free after qkv (12.6 MB >= 8.4 MB)

  tw_kernel   <<<NH_ * 3 * (H_ / 64), 256, 0, stream>>>(W, WtHi, WtLo);
  swl_kernel  <<<(SZL / 4) / 256, 256, 0, stream>>>(Wl, WlH);
  qkv_kernel  <<<B_ * NH_ * (S_ / 64), 256, 0, stream>>>(
      x, WtHi, WtLo, Kh, Qh, VTh);
  stats_kernel<<<B_ * NH_ * (S_ / 64), 256, 0, stream>>>(Kh, Qh, csuminv);
  scale_kernel<<<B_ * NH_ * 16, 256, 0, stream>>>(VTh, csuminv, mask, Cbuf);
  av_kernel   <<<B_ * NH_ * (S_ / 32), 256, 0, stream>>>(
      Kh, Qh, VTh, Cbuf, hidh);
  final_kernel<<<(B_ * S_ / 64) * (H_ / 64), 256, 0, stream>>>(
      hidh, WlH, bl, out);
}

// Round 7
// 364.629 us; speedup vs baseline: 38.4109x; 1.2287x over previous
//
#include <hip/hip_runtime.h>

// Problem constants (B,S,H,NH,P) = (2,2048,1024,16,64)
#define B_ 2
#define S_ 2048
#define H_ 1024
#define NH_ 16
#define P_ 64

using f32x4 = __attribute__((ext_vector_type(4))) float;
using i32x4 = __attribute__((ext_vector_type(4))) int;
using s16x8 = __attribute__((ext_vector_type(8))) short;
using s16x4 = __attribute__((ext_vector_type(4))) short;
using f16   = _Float16;
using f16x8 = __attribute__((ext_vector_type(8))) f16;
using f16x4 = __attribute__((ext_vector_type(4))) f16;

static __device__ __forceinline__ short f2bf(float f) {
  unsigned u = __float_as_uint(f);
  unsigned r = (u + 0x7fffu + ((u >> 16) & 1u)) >> 16;
  return (short)r;
}
static __device__ __forceinline__ float bf2f(short s) {
  return __uint_as_float(((unsigned)(unsigned short)s) << 16);
}
static __device__ __forceinline__ s16x8 ld8(const short* p) { return *(const s16x8*)p; }
static __device__ __forceinline__ f16x8 ldh8(const f16* p) { return *(const f16x8*)p; }
static __device__ __forceinline__ f32x4 ld4f(const float* p) { return *(const f32x4*)p; }

// bf16x3 fused: c += ahi*bhi + ahi*blo + alo*bhi  (qkv projection accuracy)
static __device__ __forceinline__ f32x4 mm3(s16x8 ah, s16x8 al, s16x8 bh, s16x8 bl, f32x4 c) {
  c = __builtin_amdgcn_mfma_f32_16x16x32_bf16(ah, bh, c, 0, 0, 0);
  c = __builtin_amdgcn_mfma_f32_16x16x32_bf16(ah, bl, c, 0, 0, 0);
  c = __builtin_amdgcn_mfma_f32_16x16x32_bf16(al, bh, c, 0, 0, 0);
  return c;
}
static __device__ __forceinline__ f32x4 mm16(f16x8 a, f16x8 b, f32x4 c) {
  return __builtin_amdgcn_mfma_f32_16x16x32_f16(a, b, c, 0, 0, 0);
}

// ---------------------------------------------------------------------------
// Prep A: transpose+split W [NH][3][H][P] fp32 -> Wt hi/lo [NH][3][P][H] bf16
// ---------------------------------------------------------------------------
__global__ __launch_bounds__(256) void tw_kernel(
    const float* __restrict__ W, short* __restrict__ WtHi, short* __restrict__ WtLo)
{
  __shared__ float T[64 * 65];
  const int tid = threadIdx.x;
  const int nt = blockIdx.x >> 4;
  const int h0 = (blockIdx.x & 15) * 64;
  const float* src = W + (size_t)nt * H_ * P_ + (size_t)h0 * P_;
  #pragma unroll
  for (int r = 0; r < 4; ++r) {
    int idx = tid + r * 256;
    int h = idx >> 4, p4 = (idx & 15) << 2;
    f32x4 v = ld4f(src + (size_t)h * P_ + p4);
    #pragma unroll
    for (int i = 0; i < 4; ++i) T[(p4 + i) * 65 + h] = v[i];
  }
  __syncthreads();
  short* dh = WtHi + (size_t)nt * P_ * H_;
  short* dl = WtLo + (size_t)nt * P_ * H_;
  #pragma unroll
  for (int r = 0; r < 4; ++r) {
    int idx = tid + r * 256;
    int p = idx >> 4, h4 = (idx & 15) << 2;
    s16x4 hv, lv;
    #pragma unroll
    for (int i = 0; i < 4; ++i) {
      float f = T[p * 65 + h4 + i];
      short hh = f2bf(f);
      hv[i] = hh;
      lv[i] = f2bf(f - bf2f(hh));
    }
    *(s16x4*)(dh + (size_t)p * H_ + h0 + h4) = hv;
    *(s16x4*)(dl + (size_t)p * H_ + h0 + h4) = lv;
  }
}

// ---------------------------------------------------------------------------
// Prep B: convert Wl [H][H] fp32 -> fp16
// ---------------------------------------------------------------------------
__global__ __launch_bounds__(256) void swl_kernel(
    const float* __restrict__ Wl, f16* __restrict__ WlH)
{
  int idx = blockIdx.x * 256 + threadIdx.x;
  f32x4 v = ((const f32x4*)Wl)[idx];
  f16x4 h;
  #pragma unroll
  for (int i = 0; i < 4; ++i) h[i] = (f16)v[i];
  ((f16x4*)WlH)[idx] = h;
}

// ---------------------------------------------------------------------------
// Kernel 1: QKV via MFMA bf16x3 (accurate); outputs stored single fp16.
// K,Q -> [bn][s][p]; V -> VT[bn][p][s].
// ---------------------------------------------------------------------------
__global__ __launch_bounds__(256) void qkv_kernel(
    const float* __restrict__ x,
    const short* __restrict__ WtHi, const short* __restrict__ WtLo,
    f16* __restrict__ Kh, f16* __restrict__ Qh, f16* __restrict__ VTh)
{
  __shared__ short xh_lds[2][64 * 32];
  __shared__ short xl_lds[2][64 * 32];

  int blk = blockIdx.x;
  const int st = blk & 31; blk >>= 5;
  const int n = blk & 15;
  const int b = blk >> 4;
  const int s0 = st * 64;
  const int tid = threadIdx.x;
  const int w = tid >> 6, lane = tid & 63, q = lane >> 4, fr = lane & 15;
  const int bn = b * NH_ + n;

  const int srow = tid >> 2, scc = tid & 3;
  const float* xsrc = x + ((size_t)b * S_ + s0 + srow) * H_ + 8 * scc;
  const int saddr = srow * 32 + ((scc ^ (srow & 3)) * 8);

  auto stage = [&](int k0, int bufsel) {
    f32x4 v0 = ld4f(xsrc + k0);
    f32x4 v1 = ld4f(xsrc + k0 + 4);
    s16x8 hv, lv;
    #pragma unroll
    for (int e = 0; e < 4; ++e) {
      short h0 = f2bf(v0[e]); hv[e] = h0; lv[e] = f2bf(v0[e] - bf2f(h0));
      short h1 = f2bf(v1[e]); hv[e + 4] = h1; lv[e + 4] = f2bf(v1[e] - bf2f(h1));
    }
    *(s16x8*)&xh_lds[bufsel][saddr] = hv;
    *(s16x8*)&xl_lds[bufsel][saddr] = lv;
  };

  const short* WtK  = WtHi + ((size_t)(n * 3 + 0) * P_ + 16 * w + fr) * H_ + 8 * q;
  const short* WtKl = WtLo + ((size_t)(n * 3 + 0) * P_ + 16 * w + fr) * H_ + 8 * q;
  const short* WtV  = WtHi + ((size_t)(n * 3 + 1) * P_ + 16 * w + fr) * H_ + 8 * q;
  const short* WtVl = WtLo + ((size_t)(n * 3 + 1) * P_ + 16 * w + fr) * H_ + 8 * q;
  const short* WtQ  = WtHi + ((size_t)(n * 3 + 2) * P_ + 16 * w + fr) * H_ + 8 * q;
  const short* WtQl = WtLo + ((size_t)(n * 3 + 2) * P_ + 16 * w + fr) * H_ + 8 * q;

  f32x4 accK[4] = {}, accQ[4] = {}, accV[4] = {};

  stage(0, 0);
  for (int step = 0; step < 32; ++step) {
    __syncthreads();
    if (step < 31) stage((step + 1) * 32, (step + 1) & 1);
    const int bs = step & 1;
    const int k0 = step * 32;

    s16x8 xh[4], xl[4];
    #pragma unroll
    for (int ss = 0; ss < 4; ++ss) {
      int addr = (16 * ss + fr) * 32 + ((q ^ (fr & 3)) * 8);
      xh[ss] = *(const s16x8*)&xh_lds[bs][addr];
      xl[ss] = *(const s16x8*)&xl_lds[bs][addr];
    }
    s16x8 wkh = ld8(WtK + k0),  wkl = ld8(WtKl + k0);
    s16x8 wqh = ld8(WtQ + k0),  wql = ld8(WtQl + k0);
    s16x8 wvh = ld8(WtV + k0),  wvl = ld8(WtVl + k0);
    #pragma unroll
    for (int ss = 0; ss < 4; ++ss) {
      accK[ss] = mm3(wkh, wkl, xh[ss], xl[ss], accK[ss]);
      accQ[ss] = mm3(wqh, wql, xh[ss], xl[ss], accQ[ss]);
      accV[ss] = mm3(xh[ss], xl[ss], wvh, wvl, accV[ss]);
    }
  }

  // K/Q epilogue: lane holds s = s0+16ss+fr, p = 16w+4q+c
  #pragma unroll
  for (int ss = 0; ss < 4; ++ss) {
    f16x4 hK, hQ;
    #pragma unroll
    for (int c = 0; c < 4; ++c) {
      hK[c] = (f16)accK[ss][c];
      hQ[c] = (f16)accQ[ss][c];
    }
    size_t off = ((size_t)bn * S_ + (s0 + 16 * ss + fr)) * P_ + 16 * w + 4 * q;
    *(f16x4*)(Kh + off) = hK;
    *(f16x4*)(Qh + off) = hQ;
  }
  // V epilogue: lane holds s = s0+16ss+4q+c, p = 16w+fr -> VT[p][s]
  #pragma unroll
  for (int ss = 0; ss < 4; ++ss) {
    f16x4 hV;
    #pragma unroll
    for (int c = 0; c < 4; ++c) hV[c] = (f16)accV[ss][c];
    size_t off = ((size_t)bn * P_ + (16 * w + fr)) * S_ + s0 + 16 * ss + 4 * q;
    *(f16x4*)(VTh + off) = hV;
  }
}

// ---------------------------------------------------------------------------
// Kernel 2: column sum-exp. Per-lane accumulation, double-buffered K prefetch.
// ---------------------------------------------------------------------------
__global__ __launch_bounds__(256) void stats_kernel(
    const f16* __restrict__ Kh, const f16* __restrict__ Qh,
    float* __restrict__ csuminv)
{
  __shared__ float zbuf[2 * 64];
  const int tid = threadIdx.x;
  const int bid = blockIdx.x;
  const int j0 = (bid & 31) * 64;
  const int bn = bid >> 5;
  const int w = tid >> 6, lane = tid & 63, q = lane >> 4, fr = lane & 15;
  const int jb = 32 * (w & 1), ih = w >> 1, ib0 = 32 * ih;

  f16x8 qf[2][2];
  #pragma unroll
  for (int jt = 0; jt < 2; ++jt)
    #pragma unroll
    for (int ks = 0; ks < 2; ++ks)
      qf[jt][ks] = ldh8(Qh + ((size_t)bn * S_ + (j0 + jb + 16 * jt + fr)) * P_ + 8 * q + 32 * ks);

  f32x4 z[2] = {};
  f16x8 kA[2][2], kB[2][2];

  auto loadK = [&](f16x8 (&kf)[2][2], int i0) {
    #pragma unroll
    for (int it = 0; it < 2; ++it)
      #pragma unroll
      for (int ks = 0; ks < 2; ++ks)
        kf[it][ks] = ldh8(Kh + ((size_t)bn * S_ + (i0 + ib0 + 16 * it + fr)) * P_ + 8 * q + 32 * ks);
  };
  auto step = [&](f16x8 (&kf)[2][2]) {
    f32x4 sc[2][2] = {};
    #pragma unroll
    for (int ks = 0; ks < 2; ++ks)
      #pragma unroll
      for (int jt = 0; jt < 2; ++jt)
        #pragma unroll
        for (int it = 0; it < 2; ++it)
          sc[jt][it] = mm16(qf[jt][ks], kf[it][ks], sc[jt][it]);
    #pragma unroll
    for (int jt = 0; jt < 2; ++jt)
      #pragma unroll
      for (int c = 0; c < 4; ++c)
        z[jt][c] += __expf(sc[jt][0][c] * 0.125f) + __expf(sc[jt][1][c] * 0.125f);
  };

  loadK(kA, 0);
  for (int i0 = 0; i0 < S_; i0 += 128) {
    loadK(kB, i0 + 64);
    step(kA);
    loadK(kA, (i0 + 128) & (S_ - 1));
    step(kB);
  }

  #pragma unroll
  for (int msk = 1; msk <= 8; msk <<= 1)
    #pragma unroll
    for (int jt = 0; jt < 2; ++jt)
      #pragma unroll
      for (int c = 0; c < 4; ++c)
        z[jt][c] += __shfl_xor(z[jt][c], msk, 64);

  if (fr == 0) {
    #pragma unroll
    for (int jt = 0; jt < 2; ++jt)
      *(f32x4*)&zbuf[ih * 64 + jb + 16 * jt + 4 * q] = z[jt];
  }
  __syncthreads();
  if (tid < 64)
    csuminv[(size_t)bn * S_ + j0 + tid] = 1.0f / (zbuf[tid] + zbuf[64 + tid]);
}

// ---------------------------------------------------------------------------
// Kernel 2.5: V' = mask ? zinv*V : 0 (in-place on VT); C[bn][p] = (1/S)*sum
// of masked-out V. grid = B*NH*16 blocks; wave per p-row.
// ---------------------------------------------------------------------------
__global__ __launch_bounds__(256) void scale_kernel(
    f16* __restrict__ VT, const float* __restrict__ csuminv,
    const int* __restrict__ mask, float* __restrict__ Cbuf)
{
  const int bid = blockIdx.x;
  const int bn = bid >> 4;
  const int b = bn >> 4;
  const int p = (bid & 15) * 4 + (threadIdx.x >> 6);
  const int lane = threadIdx.x & 63;
  f16* row = VT + ((size_t)bn * P_ + p) * S_;
  const float* zr = csuminv + (size_t)bn * S_;
  const int* mr = mask + (size_t)b * S_;
  float acc = 0.0f;
  #pragma unroll
  for (int k = 0; k < 4; ++k) {
    int s = (lane + 64 * k) * 8;
    f16x8 v = *(const f16x8*)(row + s);
    f32x4 z0 = ld4f(zr + s), z1 = ld4f(zr + s + 4);
    i32x4 m0 = *(const i32x4*)(mr + s), m1 = *(const i32x4*)(mr + s + 4);
    f16x8 o;
    #pragma unroll
    for (int e = 0; e < 4; ++e) {
      float fv = (float)v[e];
      if (m0[e] != 0) o[e] = (f16)(fv * z0[e]);
      else { o[e] = (f16)0.0f; acc += fv; }
      float fv2 = (float)v[e + 4];
      if (m1[e] != 0) o[e + 4] = (f16)(fv2 * z1[e]);
      else { o[e + 4] = (f16)0.0f; acc += fv2; }
    }
    *(f16x8*)(row + s) = o;
  }
  #pragma unroll
  for (int msk = 1; msk <= 32; msk <<= 1) acc += __shfl_xor(acc, msk, 64);
  if (lane == 0) Cbuf[bn * P_ + p] = acc * (1.0f / S_);
}

// ---------------------------------------------------------------------------
// Kernel 3: AV pass. Block=(bn, i-tile 64), j-step 128, 16 steps.
// 4 waves = (j-half jw) x (i-half iw). K frags fixed per block (preloaded).
// E tile [64 i][128 j] fp16 double-buffered in LDS; 1 barrier/step.
// out[i] = sum_j exp(s_ij)*V'[j] + C.  hid written fp16.
// ---------------------------------------------------------------------------
__global__ __launch_bounds__(256) void av_kernel(
    const f16* __restrict__ Kh, const f16* __restrict__ Qh,
    const f16* __restrict__ VT, const float* __restrict__ Cbuf,
    f16* __restrict__ hidh)
{
  __shared__ f16 elds[2][64 * 128];
  const int tid = threadIdx.x;
  const int bid = blockIdx.x;
  const int i0 = (bid & 31) * 64;
  const int bn = bid >> 5;
  const int b = bn >> 4, n = bn & 15;
  const int w = tid >> 6, lane = tid & 63, q = lane >> 4, fr = lane & 15;
  const int jw = (w & 1) * 64;   // j-half within 128-step
  const int pw = (w & 1) * 32;   // p-half for PV
  const int iw = (w >> 1) * 32;  // i-half

  // K b-frags fixed for the block: rows i0+iw+16it+fr
  f16x8 kf[2][2];
  #pragma unroll
  for (int it = 0; it < 2; ++it)
    #pragma unroll
    for (int ks = 0; ks < 2; ++ks)
      kf[it][ks] = ldh8(Kh + ((size_t)bn * S_ + (i0 + iw + 16 * it + fr)) * P_ + 8 * q + 32 * ks);

  f32x4 opv[2][2] = {};

  for (int T = 0; T < S_ / 128; ++T) {
    const int j0 = T * 128;
    const int buf = T & 1;

    // QK: E rows j (jw..jw+63), cols i (iw..iw+31)
    f16x8 aq[4][2];
    #pragma unroll
    for (int jt = 0; jt < 4; ++jt)
      #pragma unroll
      for (int ks = 0; ks < 2; ++ks)
        aq[jt][ks] = ldh8(Qh + ((size_t)bn * S_ + (j0 + jw + 16 * jt + fr)) * P_ + 8 * q + 32 * ks);
    f32x4 sc[4][2] = {};
    #pragma unroll
    for (int ks = 0; ks < 2; ++ks)
      #pragma unroll
      for (int jt = 0; jt < 4; ++jt)
        #pragma unroll
        for (int it = 0; it < 2; ++it)
          sc[jt][it] = mm16(aq[jt][ks], kf[it][ks], sc[jt][it]);

    #pragma unroll
    for (int jt = 0; jt < 4; ++jt)
      #pragma unroll
      for (int it = 0; it < 2; ++it) {
        f16x4 h4;
        #pragma unroll
        for (int c = 0; c < 4; ++c) h4[c] = (f16)__expf(sc[jt][it][c] * 0.125f);
        int row = iw + 16 * it + fr;
        int col = jw + 16 * jt + 4 * q;
        int addr = (row * 256 + col * 2) ^ ((row & 7) << 4);
        *(f16x4*)((char*)elds[buf] + addr) = h4;
      }
    __syncthreads();

    // PV: D2[p (pw..pw+31)][i (iw..iw+31)], k = j 128
    #pragma unroll
    for (int ks2 = 0; ks2 < 4; ++ks2) {
      f16x8 va[2];
      #pragma unroll
      for (int pt = 0; pt < 2; ++pt)
        va[pt] = ldh8(VT + ((size_t)bn * P_ + (pw + 16 * pt + fr)) * S_ + j0 + 32 * ks2 + 8 * q);
      f16x8 ef[2];
      #pragma unroll
      for (int it = 0; it < 2; ++it) {
        int row = iw + 16 * it + fr;
        int addr = (row * 256 + (32 * ks2 + 8 * q) * 2) ^ ((row & 7) << 4);
        ef[it] = *(const f16x8*)((const char*)elds[buf] + addr);
      }
      #pragma unroll
      for (int pt = 0; pt < 2; ++pt)
        #pragma unroll
        for (int it = 0; it < 2; ++it)
          opv[pt][it] = mm16(va[pt], ef[it], opv[pt][it]);
    }
  }

  // epilogue: lane holds p = pw+16pt+4q+c, i = i0+iw+16it+fr
  #pragma unroll
  for (int pt = 0; pt < 2; ++pt) {
    const int pcol = pw + 16 * pt + 4 * q;
    f32x4 cv = ld4f(Cbuf + bn * P_ + pcol);
    #pragma unroll
    for (int it = 0; it < 2; ++it) {
      f16x4 hv;
      #pragma unroll
      for (int c = 0; c < 4; ++c) hv[c] = (f16)(opv[pt][it][c] + cv[c]);
      *(f16x4*)(hidh + ((size_t)b * S_ + (i0 + iw + 16 * it + fr)) * H_ + n * P_ + pcol) = hv;
    }
  }
}

// ---------------------------------------------------------------------------
// Kernel 4: out = hid @ Wl.T + bl via fp16 MFMA. hid tile staged in LDS.
// ---------------------------------------------------------------------------
__global__ __launch_bounds__(256) void final_kernel(
    const f16* __restrict__ hidh, const f16* __restrict__ WlH,
    const float* __restrict__ bl, float* __restrict__ out)
{
  __shared__ f16 hl[2][64 * 32];
  const int tid = threadIdx.x;
  const int ot = blockIdx.x & 15;
  const int rt = blockIdx.x >> 4;
  const int r0 = rt * 64, o0 = ot * 64;
  const int w = tid >> 6, lane = tid & 63, q = lane >> 4, fr = lane & 15;

  const int srow = tid >> 2, scc = tid & 3;
  const f16* hsrc = hidh + (size_t)(r0 + srow) * H_ + 8 * scc;
  const int saddr = srow * 32 + ((scc ^ (srow & 3)) * 8);

  auto stage = [&](int k0, int bufsel) {
    *(f16x8*)&hl[bufsel][saddr] = ldh8(hsrc + k0);
  };

  const f16* WlA = WlH + ((size_t)(o0 + 16 * w + fr)) * H_ + 8 * q;

  f32x4 acc[4] = {};

  stage(0, 0);
  for (int step = 0; step < 32; ++step) {
    __syncthreads();
    if (step < 31) stage((step + 1) * 32, (step + 1) & 1);
    const int bs = step & 1;
    const int k0 = step * 32;

    f16x8 bh[4];
    #pragma unroll
    for (int ss = 0; ss < 4; ++ss) {
      int addr = (16 * ss + fr) * 32 + ((q ^ (fr & 3)) * 8);
      bh[ss] = *(const f16x8*)&hl[bs][addr];
    }
    f16x8 ah = ldh8(WlA + k0);
    #pragma unroll
    for (int ss = 0; ss < 4; ++ss)
      acc[ss] = mm16(ah, bh[ss], acc[ss]);
  }

  const int o = o0 + 16 * w + 4 * q;
  f32x4 bv = ld4f(bl + o);
  #pragma unroll
  for (int ss = 0; ss < 4; ++ss) {
    f32x4 v;
    #pragma unroll
    for (int c = 0; c < 4; ++c) v[c] = acc[ss][c] + bv[c];
    *(f32x4*)(out + (size_t)(r0 + 16 * ss + fr) * H_ + o) = v;
  }
}

// ---------------------------------------------------------------------------
extern "C" void kernel_launch(void* const* d_in, const int* in_sizes, int n_in,
                              void* d_out, int out_size, void* d_ws, size_t ws_size,
                              hipStream_t stream) {
  const float* x    = (const float*)d_in[0];
  const int*   mask = (const int*)d_in[1];
  const float* W    = (const float*)d_in[2];
  const float* Wl   = (const float*)d_in[3];
  const float* bl   = (const float*)d_in[4];
  float* out = (float*)d_out;

  const size_t SZ  = (size_t)B_ * NH_ * S_ * P_;      // 4,194,304
  const size_t SZW = (size_t)NH_ * 3 * H_ * P_;       // 3,145,728
  const size_t SZL = (size_t)H_ * H_;                 // 1,048,576
  const size_t SZC = (size_t)B_ * NH_ * S_;           // 65,536

  char* p = (char*)d_ws;
  f16*   Kh   = (f16*)p;  p += SZ * 2;
  f16*   Qh   = (f16*)p;  p += SZ * 2;
  f16*   VTh  = (f16*)p;  p += SZ * 2;
  short* WtHi = (short*)p; p += SZW * 2;
  short* WtLo = (short*)p; p += SZW * 2;
  f16*   WlH  = (f16*)p;  p += SZL * 2;
  float* csuminv = (float*)p; p += SZC * 4;
  float* Cbuf    = (float*)p; p += (size_t)B_ * NH_ * P_ * 4;
  f16* hidh = (f16*)WtHi;  // alias: Wt region free after qkv (12.6 MB >= 8.4 MB)

  tw_kernel   <<<NH_ * 3 * (H_ / 64), 256, 0, stream>>>(W, WtHi, WtLo);
  swl_kernel  <<<(SZL / 4) / 256, 256, 0, stream>>>(Wl, WlH);
  qkv_kernel  <<<B_ * NH_ * (S_ / 64), 256, 0, stream>>>(
      x, WtHi, WtLo, Kh, Qh, VTh);
  stats_kernel<<<B_ * NH_ * (S_ / 64), 256, 0, stream>>>(Kh, Qh, csuminv);
  scale_kernel<<<B_ * NH_ * 16, 256, 0, stream>>>(VTh, csuminv, mask, Cbuf);
  av_kernel   <<<B_ * NH_ * (S_ / 64), 256, 0, stream>>>(
      Kh, Qh, VTh, Cbuf, hidh);
  final_kernel<<<(B_ * S_ / 64) * (H_ / 64), 256, 0, stream>>>(
      hidh, WlH, bl, out);
}

// Round 8
// 288.288 us; speedup vs baseline: 48.5824x; 1.2648x over previous
//
#include <hip/hip_runtime.h>

// Problem constants (B,S,H,NH,P) = (2,2048,1024,16,64)
#define B_ 2
#define S_ 2048
#define H_ 1024
#define NH_ 16
#define P_ 64

using f32x4 = __attribute__((ext_vector_type(4))) float;
using i32x4 = __attribute__((ext_vector_type(4))) int;
using s16x8 = __attribute__((ext_vector_type(8))) short;
using s16x4 = __attribute__((ext_vector_type(4))) short;
using f16   = _Float16;
using f16x8 = __attribute__((ext_vector_type(8))) f16;
using f16x4 = __attribute__((ext_vector_type(4))) f16;

static __device__ __forceinline__ short f2bf(float f) {
  unsigned u = __float_as_uint(f);
  unsigned r = (u + 0x7fffu + ((u >> 16) & 1u)) >> 16;
  return (short)r;
}
static __device__ __forceinline__ float bf2f(short s) {
  return __uint_as_float(((unsigned)(unsigned short)s) << 16);
}
static __device__ __forceinline__ s16x8 ld8(const short* p) { return *(const s16x8*)p; }
static __device__ __forceinline__ f16x8 ldh8(const f16* p) { return *(const f16x8*)p; }
static __device__ __forceinline__ f32x4 ld4f(const float* p) { return *(const f32x4*)p; }

// bf16x3 fused: c += ahi*bhi + ahi*blo + alo*bhi  (qkv projection accuracy)
static __device__ __forceinline__ f32x4 mm3(s16x8 ah, s16x8 al, s16x8 bh, s16x8 bl, f32x4 c) {
  c = __builtin_amdgcn_mfma_f32_16x16x32_bf16(ah, bh, c, 0, 0, 0);
  c = __builtin_amdgcn_mfma_f32_16x16x32_bf16(ah, bl, c, 0, 0, 0);
  c = __builtin_amdgcn_mfma_f32_16x16x32_bf16(al, bh, c, 0, 0, 0);
  return c;
}
static __device__ __forceinline__ f32x4 mm16(f16x8 a, f16x8 b, f32x4 c) {
  return __builtin_amdgcn_mfma_f32_16x16x32_f16(a, b, c, 0, 0, 0);
}

// ---------------------------------------------------------------------------
// Prep A: transpose+split W [NH][3][H][P] fp32 -> Wt hi/lo [NH][3][P][H] bf16
// ---------------------------------------------------------------------------
__global__ __launch_bounds__(256) void tw_kernel(
    const float* __restrict__ W, short* __restrict__ WtHi, short* __restrict__ WtLo)
{
  __shared__ float T[64 * 65];
  const int tid = threadIdx.x;
  const int nt = blockIdx.x >> 4;
  const int h0 = (blockIdx.x & 15) * 64;
  const float* src = W + (size_t)nt * H_ * P_ + (size_t)h0 * P_;
  #pragma unroll
  for (int r = 0; r < 4; ++r) {
    int idx = tid + r * 256;
    int h = idx >> 4, p4 = (idx & 15) << 2;
    f32x4 v = ld4f(src + (size_t)h * P_ + p4);
    #pragma unroll
    for (int i = 0; i < 4; ++i) T[(p4 + i) * 65 + h] = v[i];
  }
  __syncthreads();
  short* dh = WtHi + (size_t)nt * P_ * H_;
  short* dl = WtLo + (size_t)nt * P_ * H_;
  #pragma unroll
  for (int r = 0; r < 4; ++r) {
    int idx = tid + r * 256;
    int p = idx >> 4, h4 = (idx & 15) << 2;
    s16x4 hv, lv;
    #pragma unroll
    for (int i = 0; i < 4; ++i) {
      float f = T[p * 65 + h4 + i];
      short hh = f2bf(f);
      hv[i] = hh;
      lv[i] = f2bf(f - bf2f(hh));
    }
    *(s16x4*)(dh + (size_t)p * H_ + h0 + h4) = hv;
    *(s16x4*)(dl + (size_t)p * H_ + h0 + h4) = lv;
  }
}

// ---------------------------------------------------------------------------
// Prep B: convert Wl [H][H] fp32 -> fp16
// ---------------------------------------------------------------------------
__global__ __launch_bounds__(256) void swl_kernel(
    const float* __restrict__ Wl, f16* __restrict__ WlH)
{
  int idx = blockIdx.x * 256 + threadIdx.x;
  f32x4 v = ((const f32x4*)Wl)[idx];
  f16x4 h;
  #pragma unroll
  for (int i = 0; i < 4; ++i) h[i] = (f16)v[i];
  ((f16x4*)WlH)[idx] = h;
}

// ---------------------------------------------------------------------------
// Kernel 1: QKV via MFMA bf16x3 (accurate); outputs stored single fp16.
// K,Q -> [bn][s][p]; V -> VT[bn][p][s].
// ---------------------------------------------------------------------------
__global__ __launch_bounds__(256) void qkv_kernel(
    const float* __restrict__ x,
    const short* __restrict__ WtHi, const short* __restrict__ WtLo,
    f16* __restrict__ Kh, f16* __restrict__ Qh, f16* __restrict__ VTh)
{
  __shared__ short xh_lds[2][64 * 32];
  __shared__ short xl_lds[2][64 * 32];

  int blk = blockIdx.x;
  const int st = blk & 31; blk >>= 5;
  const int n = blk & 15;
  const int b = blk >> 4;
  const int s0 = st * 64;
  const int tid = threadIdx.x;
  const int w = tid >> 6, lane = tid & 63, q = lane >> 4, fr = lane & 15;
  const int bn = b * NH_ + n;

  const int srow = tid >> 2, scc = tid & 3;
  const float* xsrc = x + ((size_t)b * S_ + s0 + srow) * H_ + 8 * scc;
  const int saddr = srow * 32 + ((scc ^ (srow & 3)) * 8);

  auto stage = [&](int k0, int bufsel) {
    f32x4 v0 = ld4f(xsrc + k0);
    f32x4 v1 = ld4f(xsrc + k0 + 4);
    s16x8 hv, lv;
    #pragma unroll
    for (int e = 0; e < 4; ++e) {
      short h0 = f2bf(v0[e]); hv[e] = h0; lv[e] = f2bf(v0[e] - bf2f(h0));
      short h1 = f2bf(v1[e]); hv[e + 4] = h1; lv[e + 4] = f2bf(v1[e] - bf2f(h1));
    }
    *(s16x8*)&xh_lds[bufsel][saddr] = hv;
    *(s16x8*)&xl_lds[bufsel][saddr] = lv;
  };

  const short* WtK  = WtHi + ((size_t)(n * 3 + 0) * P_ + 16 * w + fr) * H_ + 8 * q;
  const short* WtKl = WtLo + ((size_t)(n * 3 + 0) * P_ + 16 * w + fr) * H_ + 8 * q;
  const short* WtV  = WtHi + ((size_t)(n * 3 + 1) * P_ + 16 * w + fr) * H_ + 8 * q;
  const short* WtVl = WtLo + ((size_t)(n * 3 + 1) * P_ + 16 * w + fr) * H_ + 8 * q;
  const short* WtQ  = WtHi + ((size_t)(n * 3 + 2) * P_ + 16 * w + fr) * H_ + 8 * q;
  const short* WtQl = WtLo + ((size_t)(n * 3 + 2) * P_ + 16 * w + fr) * H_ + 8 * q;

  f32x4 accK[4] = {}, accQ[4] = {}, accV[4] = {};

  stage(0, 0);
  for (int step = 0; step < 32; ++step) {
    __syncthreads();
    if (step < 31) stage((step + 1) * 32, (step + 1) & 1);
    const int bs = step & 1;
    const int k0 = step * 32;

    s16x8 xh[4], xl[4];
    #pragma unroll
    for (int ss = 0; ss < 4; ++ss) {
      int addr = (16 * ss + fr) * 32 + ((q ^ (fr & 3)) * 8);
      xh[ss] = *(const s16x8*)&xh_lds[bs][addr];
      xl[ss] = *(const s16x8*)&xl_lds[bs][addr];
    }
    s16x8 wkh = ld8(WtK + k0),  wkl = ld8(WtKl + k0);
    s16x8 wqh = ld8(WtQ + k0),  wql = ld8(WtQl + k0);
    s16x8 wvh = ld8(WtV + k0),  wvl = ld8(WtVl + k0);
    #pragma unroll
    for (int ss = 0; ss < 4; ++ss) {
      accK[ss] = mm3(wkh, wkl, xh[ss], xl[ss], accK[ss]);
      accQ[ss] = mm3(wqh, wql, xh[ss], xl[ss], accQ[ss]);
      accV[ss] = mm3(xh[ss], xl[ss], wvh, wvl, accV[ss]);
    }
  }

  // K/Q epilogue: lane holds s = s0+16ss+fr, p = 16w+4q+c
  #pragma unroll
  for (int ss = 0; ss < 4; ++ss) {
    f16x4 hK, hQ;
    #pragma unroll
    for (int c = 0; c < 4; ++c) {
      hK[c] = (f16)accK[ss][c];
      hQ[c] = (f16)accQ[ss][c];
    }
    size_t off = ((size_t)bn * S_ + (s0 + 16 * ss + fr)) * P_ + 16 * w + 4 * q;
    *(f16x4*)(Kh + off) = hK;
    *(f16x4*)(Qh + off) = hQ;
  }
  // V epilogue: lane holds s = s0+16ss+4q+c, p = 16w+fr -> VT[p][s]
  #pragma unroll
  for (int ss = 0; ss < 4; ++ss) {
    f16x4 hV;
    #pragma unroll
    for (int c = 0; c < 4; ++c) hV[c] = (f16)accV[ss][c];
    size_t off = ((size_t)bn * P_ + (16 * w + fr)) * S_ + s0 + 16 * ss + 4 * q;
    *(f16x4*)(VTh + off) = hV;
  }
}

// ---------------------------------------------------------------------------
// Kernel 2: column sum-exp. Per-lane accumulation, double-buffered K prefetch.
// ---------------------------------------------------------------------------
__global__ __launch_bounds__(256) void stats_kernel(
    const f16* __restrict__ Kh, const f16* __restrict__ Qh,
    float* __restrict__ csuminv)
{
  __shared__ float zbuf[2 * 64];
  const int tid = threadIdx.x;
  const int bid = blockIdx.x;
  const int j0 = (bid & 31) * 64;
  const int bn = bid >> 5;
  const int w = tid >> 6, lane = tid & 63, q = lane >> 4, fr = lane & 15;
  const int jb = 32 * (w & 1), ih = w >> 1, ib0 = 32 * ih;

  f16x8 qf[2][2];
  #pragma unroll
  for (int jt = 0; jt < 2; ++jt)
    #pragma unroll
    for (int ks = 0; ks < 2; ++ks)
      qf[jt][ks] = ldh8(Qh + ((size_t)bn * S_ + (j0 + jb + 16 * jt + fr)) * P_ + 8 * q + 32 * ks);

  f32x4 z[2] = {};
  f16x8 kA[2][2], kB[2][2];

  auto loadK = [&](f16x8 (&kf)[2][2], int i0) {
    #pragma unroll
    for (int it = 0; it < 2; ++it)
      #pragma unroll
      for (int ks = 0; ks < 2; ++ks)
        kf[it][ks] = ldh8(Kh + ((size_t)bn * S_ + (i0 + ib0 + 16 * it + fr)) * P_ + 8 * q + 32 * ks);
  };
  auto step = [&](f16x8 (&kf)[2][2]) {
    f32x4 sc[2][2] = {};
    #pragma unroll
    for (int ks = 0; ks < 2; ++ks)
      #pragma unroll
      for (int jt = 0; jt < 2; ++jt)
        #pragma unroll
        for (int it = 0; it < 2; ++it)
          sc[jt][it] = mm16(qf[jt][ks], kf[it][ks], sc[jt][it]);
    #pragma unroll
    for (int jt = 0; jt < 2; ++jt)
      #pragma unroll
      for (int c = 0; c < 4; ++c)
        z[jt][c] += __expf(sc[jt][0][c] * 0.125f) + __expf(sc[jt][1][c] * 0.125f);
  };

  loadK(kA, 0);
  for (int i0 = 0; i0 < S_; i0 += 128) {
    loadK(kB, i0 + 64);
    step(kA);
    loadK(kA, (i0 + 128) & (S_ - 1));
    step(kB);
  }

  #pragma unroll
  for (int msk = 1; msk <= 8; msk <<= 1)
    #pragma unroll
    for (int jt = 0; jt < 2; ++jt)
      #pragma unroll
      for (int c = 0; c < 4; ++c)
        z[jt][c] += __shfl_xor(z[jt][c], msk, 64);

  if (fr == 0) {
    #pragma unroll
    for (int jt = 0; jt < 2; ++jt)
      *(f32x4*)&zbuf[ih * 64 + jb + 16 * jt + 4 * q] = z[jt];
  }
  __syncthreads();
  if (tid < 64)
    csuminv[(size_t)bn * S_ + j0 + tid] = 1.0f / (zbuf[tid] + zbuf[64 + tid]);
}

// ---------------------------------------------------------------------------
// Kernel 2.5: V' = mask ? zinv*V : 0 (in-place on VT); C[bn][p] = (1/S)*sum
// of masked-out V. grid = B*NH*16 blocks; wave per p-row.
// ---------------------------------------------------------------------------
__global__ __launch_bounds__(256) void scale_kernel(
    f16* __restrict__ VT, const float* __restrict__ csuminv,
    const int* __restrict__ mask, float* __restrict__ Cbuf)
{
  const int bid = blockIdx.x;
  const int bn = bid >> 4;
  const int b = bn >> 4;
  const int p = (bid & 15) * 4 + (threadIdx.x >> 6);
  const int lane = threadIdx.x & 63;
  f16* row = VT + ((size_t)bn * P_ + p) * S_;
  const float* zr = csuminv + (size_t)bn * S_;
  const int* mr = mask + (size_t)b * S_;
  float acc = 0.0f;
  #pragma unroll
  for (int k = 0; k < 4; ++k) {
    int s = (lane + 64 * k) * 8;
    f16x8 v = *(const f16x8*)(row + s);
    f32x4 z0 = ld4f(zr + s), z1 = ld4f(zr + s + 4);
    i32x4 m0 = *(const i32x4*)(mr + s), m1 = *(const i32x4*)(mr + s + 4);
    f16x8 o;
    #pragma unroll
    for (int e = 0; e < 4; ++e) {
      float fv = (float)v[e];
      if (m0[e] != 0) o[e] = (f16)(fv * z0[e]);
      else { o[e] = (f16)0.0f; acc += fv; }
      float fv2 = (float)v[e + 4];
      if (m1[e] != 0) o[e + 4] = (f16)(fv2 * z1[e]);
      else { o[e + 4] = (f16)0.0f; acc += fv2; }
    }
    *(f16x8*)(row + s) = o;
  }
  #pragma unroll
  for (int msk = 1; msk <= 32; msk <<= 1) acc += __shfl_xor(acc, msk, 64);
  if (lane == 0) Cbuf[bn * P_ + p] = acc * (1.0f / S_);
}

// ---------------------------------------------------------------------------
// Kernel 3: AV pass, barrier-free hot loop (wave-private E slices).
// Block=(bn, i-tile 64); wave w owns j-slices {T*128 + w*32}.
// Per wave: K frags fixed (full i 64); per step: QK (16 mfma) -> exp ->
// E[i][j] in private LDS (pitch 40 f16) -> PV (16 mfma) into opv[p][i].
// Epilogue: 4-round LDS reduce of the 4 j-partials, + C, write hid fp16.
// ---------------------------------------------------------------------------
__global__ __launch_bounds__(256) void av_kernel(
    const f16* __restrict__ Kh, const f16* __restrict__ Qh,
    const f16* __restrict__ VT, const float* __restrict__ Cbuf,
    f16* __restrict__ hidh)
{
  __shared__ f16  elds[4][64 * 40];   // per-wave E slice, pitch 40 f16 (80 B)
  __shared__ float accl[64 * 68];     // [i][p] fp32 accumulator, pitch 68
  const int tid = threadIdx.x;
  const int bid = blockIdx.x;
  const int i0 = (bid & 31) * 64;
  const int bn = bid >> 5;
  const int b = bn >> 4, n = bn & 15;
  const int w = tid >> 6, lane = tid & 63, q = lane >> 4, fr = lane & 15;
  f16* ew = &elds[w][0];

  // K b-frags fixed: rows i = i0+16it+fr (full 64-i tile)
  f16x8 kf[4][2];
  #pragma unroll
  for (int it = 0; it < 4; ++it)
    #pragma unroll
    for (int ks = 0; ks < 2; ++ks)
      kf[it][ks] = ldh8(Kh + ((size_t)bn * S_ + (i0 + 16 * it + fr)) * P_ + 8 * q + 32 * ks);

  f32x4 opv[4][4] = {};   // [pt][it]: p = 16pt+4q+c, i = 16it+fr

  for (int T = 0; T < S_ / 128; ++T) {
    const int j0 = T * 128 + w * 32;

    // independent global loads for this step (compiler prefetches freely)
    f16x8 aq[2][2];
    #pragma unroll
    for (int jt = 0; jt < 2; ++jt)
      #pragma unroll
      for (int ks = 0; ks < 2; ++ks)
        aq[jt][ks] = ldh8(Qh + ((size_t)bn * S_ + (j0 + 16 * jt + fr)) * P_ + 8 * q + 32 * ks);
    f16x8 va[4];
    #pragma unroll
    for (int pt = 0; pt < 4; ++pt)
      va[pt] = ldh8(VT + ((size_t)bn * P_ + (16 * pt + fr)) * S_ + j0 + 8 * q);

    // QK + exp + private-E write, per it (keeps sc live-range small)
    #pragma unroll
    for (int it = 0; it < 4; ++it) {
      f32x4 s0 = {}, s1 = {};
      s0 = mm16(aq[0][0], kf[it][0], s0);
      s0 = mm16(aq[0][1], kf[it][1], s0);
      s1 = mm16(aq[1][0], kf[it][0], s1);
      s1 = mm16(aq[1][1], kf[it][1], s1);
      f16x4 e0, e1;
      #pragma unroll
      for (int c = 0; c < 4; ++c) {
        e0[c] = (f16)__expf(s0[c] * 0.125f);
        e1[c] = (f16)__expf(s1[c] * 0.125f);
      }
      // E[i][j]: row = 16it+fr, cols 16jt+4q..+3
      *(f16x4*)(ew + (16 * it + fr) * 40 + 4 * q)      = e0;
      *(f16x4*)(ew + (16 * it + fr) * 40 + 16 + 4 * q) = e1;
    }

    // PV: B-frag = E rows i, k = j-local 8q+e (same-wave data; lgkm ordering)
    #pragma unroll
    for (int it = 0; it < 4; ++it) {
      f16x8 ef = *(const f16x8*)(ew + (16 * it + fr) * 40 + 8 * q);
      #pragma unroll
      for (int pt = 0; pt < 4; ++pt)
        opv[pt][it] = mm16(va[pt], ef, opv[pt][it]);
    }
  }

  // ---- epilogue: reduce 4 wave-partials via LDS ----
  #pragma unroll
  for (int r = 0; r < 4; ++r) {
    __syncthreads();
    if (w == r) {
      #pragma unroll
      for (int it = 0; it < 4; ++it)
        #pragma unroll
        for (int pt = 0; pt < 4; ++pt) {
          float* a = &accl[(16 * it + fr) * 68 + 16 * pt + 4 * q];
          if (r == 0) *(f32x4*)a = opv[pt][it];
          else {
            f32x4 old = *(const f32x4*)a;
            #pragma unroll
            for (int c = 0; c < 4; ++c) old[c] += opv[pt][it][c];
            *(f32x4*)a = old;
          }
        }
    }
  }
  __syncthreads();

  // write hid: thread -> (i = tid>>2, p0 = (tid&3)*16), 16 f16 contiguous
  const int ti = tid >> 2;
  const int tp = (tid & 3) << 4;
  const float* cb = Cbuf + bn * P_ + tp;
  f16* dst = hidh + ((size_t)b * S_ + (i0 + ti)) * H_ + n * P_ + tp;
  #pragma unroll
  for (int h = 0; h < 2; ++h) {
    f32x4 a0 = *(const f32x4*)&accl[ti * 68 + tp + 8 * h];
    f32x4 a1 = *(const f32x4*)&accl[ti * 68 + tp + 8 * h + 4];
    f32x4 c0 = ld4f(cb + 8 * h);
    f32x4 c1 = ld4f(cb + 8 * h + 4);
    f16x8 o;
    #pragma unroll
    for (int e = 0; e < 4; ++e) {
      o[e]     = (f16)(a0[e] + c0[e]);
      o[e + 4] = (f16)(a1[e] + c1[e]);
    }
    *(f16x8*)(dst + 8 * h) = o;
  }
}

// ---------------------------------------------------------------------------
// Kernel 4: out = hid @ Wl.T + bl via fp16 MFMA. hid tile staged in LDS.
// ---------------------------------------------------------------------------
__global__ __launch_bounds__(256) void final_kernel(
    const f16* __restrict__ hidh, const f16* __restrict__ WlH,
    const float* __restrict__ bl, float* __restrict__ out)
{
  __shared__ f16 hl[2][64 * 32];
  const int tid = threadIdx.x;
  const int ot = blockIdx.x & 15;
  const int rt = blockIdx.x >> 4;
  const int r0 = rt * 64, o0 = ot * 64;
  const int w = tid >> 6, lane = tid & 63, q = lane >> 4, fr = lane & 15;

  const int srow = tid >> 2, scc = tid & 3;
  const f16* hsrc = hidh + (size_t)(r0 + srow) * H_ + 8 * scc;
  const int saddr = srow * 32 + ((scc ^ (srow & 3)) * 8);

  auto stage = [&](int k0, int bufsel) {
    *(f16x8*)&hl[bufsel][saddr] = ldh8(hsrc + k0);
  };

  const f16* WlA = WlH + ((size_t)(o0 + 16 * w + fr)) * H_ + 8 * q;

  f32x4 acc[4] = {};

  stage(0, 0);
  for (int step = 0; step < 32; ++step) {
    __syncthreads();
    if (step < 31) stage((step + 1) * 32, (step + 1) & 1);
    const int bs = step & 1;
    const int k0 = step * 32;

    f16x8 bh[4];
    #pragma unroll
    for (int ss = 0; ss < 4; ++ss) {
      int addr = (16 * ss + fr) * 32 + ((q ^ (fr & 3)) * 8);
      bh[ss] = *(const f16x8*)&hl[bs][addr];
    }
    f16x8 ah = ldh8(WlA + k0);
    #pragma unroll
    for (int ss = 0; ss < 4; ++ss)
      acc[ss] = mm16(ah, bh[ss], acc[ss]);
  }

  const int o = o0 + 16 * w + 4 * q;
  f32x4 bv = ld4f(bl + o);
  #pragma unroll
  for (int ss = 0; ss < 4; ++ss) {
    f32x4 v;
    #pragma unroll
    for (int c = 0; c < 4; ++c) v[c] = acc[ss][c] + bv[c];
    *(f32x4*)(out + (size_t)(r0 + 16 * ss + fr) * H_ + o) = v;
  }
}

// ---------------------------------------------------------------------------
extern "C" void kernel_launch(void* const* d_in, const int* in_sizes, int n_in,
                              void* d_out, int out_size, void* d_ws, size_t ws_size,
                              hipStream_t stream) {
  const float* x    = (const float*)d_in[0];
  const int*   mask = (const int*)d_in[1];
  const float* W    = (const float*)d_in[2];
  const float* Wl   = (const float*)d_in[3];
  const float* bl   = (const float*)d_in[4];
  float* out = (float*)d_out;

  const size_t SZ  = (size_t)B_ * NH_ * S_ * P_;      // 4,194,304
  const size_t SZW = (size_t)NH_ * 3 * H_ * P_;       // 3,145,728
  const size_t SZL = (size_t)H_ * H_;                 // 1,048,576
  const size_t SZC = (size_t)B_ * NH_ * S_;           // 65,536

  char* p = (char*)d_ws;
  f16*   Kh   = (f16*)p;  p += SZ * 2;
  f16*   Qh   = (f16*)p;  p += SZ * 2;
  f16*   VTh  = (f16*)p;  p += SZ * 2;
  short* WtHi = (short*)p; p += SZW * 2;
  short* WtLo = (short*)p; p += SZW * 2;
  f16*   WlH  = (f16*)p;  p += SZL * 2;
  float* csuminv = (float*)p; p += SZC * 4;
  float* Cbuf    = (float*)p; p += (size_t)B_ * NH_ * P_ * 4;
  f16* hidh = (f16*)WtHi;  // alias: Wt region free after qkv (12.6 MB >= 8.4 MB)

  tw_kernel   <<<NH_ * 3 * (H_ / 64), 256, 0, stream>>>(W, WtHi, WtLo);
  swl_kernel  <<<(SZL / 4) / 256, 256, 0, stream>>>(Wl, WlH);
  qkv_kernel  <<<B_ * NH_ * (S_ / 64), 256, 0, stream>>>(
      x, WtHi, WtLo, Kh, Qh, VTh);
  stats_kernel<<<B_ * NH_ * (S_ / 64), 256, 0, stream>>>(Kh, Qh, csuminv);
  scale_kernel<<<B_ * NH_ * 16, 256, 0, stream>>>(VTh, csuminv, mask, Cbuf);
  av_kernel   <<<B_ * NH_ * (S_ / 64), 256, 0, stream>>>(
      Kh, Qh, VTh, Cbuf, hidh);
  final_kernel<<<(B_ * S_ / 64) * (H_ / 64), 256, 0, stream>>>(
      hidh, WlH, bl, out);
}

// Round 9
// 235.251 us; speedup vs baseline: 59.5352x; 1.2254x over previous
//
#include <hip/hip_runtime.h>

// Problem constants (B,S,H,NH,P) = (2,2048,1024,16,64)
#define B_ 2
#define S_ 2048
#define H_ 1024
#define NH_ 16
#define P_ 64

using f32x4 = __attribute__((ext_vector_type(4))) float;
using i32x4 = __attribute__((ext_vector_type(4))) int;
using f16   = _Float16;
using f16x8 = __attribute__((ext_vector_type(8))) f16;
using f16x4 = __attribute__((ext_vector_type(4))) f16;

static __device__ __forceinline__ f16x8 ldh8(const f16* p) { return *(const f16x8*)p; }
static __device__ __forceinline__ f32x4 ld4f(const float* p) { return *(const f32x4*)p; }

static __device__ __forceinline__ f32x4 mm16(f16x8 a, f16x8 b, f32x4 c) {
  return __builtin_amdgcn_mfma_f32_16x16x32_f16(a, b, c, 0, 0, 0);
}

// ---------------------------------------------------------------------------
// Prep A: transpose W [NH][3][H][P] fp32 -> Wt fp16 [NH][3][P][H]
// ---------------------------------------------------------------------------
__global__ __launch_bounds__(256) void tw_kernel(
    const float* __restrict__ W, f16* __restrict__ WtH)
{
  __shared__ float T[64 * 65];
  const int tid = threadIdx.x;
  const int nt = blockIdx.x >> 4;
  const int h0 = (blockIdx.x & 15) * 64;
  const float* src = W + (size_t)nt * H_ * P_ + (size_t)h0 * P_;
  #pragma unroll
  for (int r = 0; r < 4; ++r) {
    int idx = tid + r * 256;
    int h = idx >> 4, p4 = (idx & 15) << 2;
    f32x4 v = ld4f(src + (size_t)h * P_ + p4);
    #pragma unroll
    for (int i = 0; i < 4; ++i) T[(p4 + i) * 65 + h] = v[i];
  }
  __syncthreads();
  f16* dh = WtH + (size_t)nt * P_ * H_;
  #pragma unroll
  for (int r = 0; r < 4; ++r) {
    int idx = tid + r * 256;
    int p = idx >> 4, h4 = (idx & 15) << 2;
    f16x4 hv;
    #pragma unroll
    for (int i = 0; i < 4; ++i) hv[i] = (f16)T[p * 65 + h4 + i];
    *(f16x4*)(dh + (size_t)p * H_ + h0 + h4) = hv;
  }
}

// ---------------------------------------------------------------------------
// Prep B: convert Wl [H][H] fp32 -> fp16
// ---------------------------------------------------------------------------
__global__ __launch_bounds__(256) void swl_kernel(
    const float* __restrict__ Wl, f16* __restrict__ WlH)
{
  int idx = blockIdx.x * 256 + threadIdx.x;
  f32x4 v = ((const f32x4*)Wl)[idx];
  f16x4 h;
  #pragma unroll
  for (int i = 0; i < 4; ++i) h[i] = (f16)v[i];
  ((f16x4*)WlH)[idx] = h;
}

// ---------------------------------------------------------------------------
// Kernel 1: QKV via single fp16 MFMA. x tile (64s x 64k) staged fp16 in LDS,
// double-buffered, chunk-XOR swizzled. Wave w owns p-subtile 16w.
// K,Q: D[p][s]=mfma(Wt,x) -> [bn][s][p] fp16 (Q pre-scaled by 1/8).
// V:   D[s][p]=mfma(x,Wt) -> VT[bn][p][s] fp16.
// ---------------------------------------------------------------------------
__global__ __launch_bounds__(256) void qkv_kernel(
    const float* __restrict__ x, const f16* __restrict__ WtH,
    f16* __restrict__ Kh, f16* __restrict__ Qh, f16* __restrict__ VTh)
{
  __shared__ f16 xls[2][64 * 64];

  int blk = blockIdx.x;
  const int st = blk & 31; blk >>= 5;
  const int n = blk & 15;
  const int b = blk >> 4;
  const int s0 = st * 64;
  const int tid = threadIdx.x;
  const int w = tid >> 6, lane = tid & 63, q = lane >> 4, fr = lane & 15;
  const int bn = b * NH_ + n;

  const int srow = tid >> 2, scc = tid & 3;   // staging: row, 16-f16 chunk pair
  const float* xsrc = x + ((size_t)b * S_ + s0 + srow) * H_ + 16 * scc;
  const int c0 = ((2 * scc) ^ (srow & 7)) * 8;
  const int c1 = ((2 * scc + 1) ^ (srow & 7)) * 8;

  auto stage = [&](int k0, int bs) {
    f32x4 v0 = ld4f(xsrc + k0),     v1 = ld4f(xsrc + k0 + 4);
    f32x4 v2 = ld4f(xsrc + k0 + 8), v3 = ld4f(xsrc + k0 + 12);
    f16x8 a, b2;
    #pragma unroll
    for (int e = 0; e < 4; ++e) {
      a[e] = (f16)v0[e];  a[e + 4] = (f16)v1[e];
      b2[e] = (f16)v2[e]; b2[e + 4] = (f16)v3[e];
    }
    *(f16x8*)&xls[bs][srow * 64 + c0] = a;
    *(f16x8*)&xls[bs][srow * 64 + c1] = b2;
  };

  const f16* WtK = WtH + ((size_t)(n * 3 + 0) * P_ + 16 * w + fr) * H_ + 8 * q;
  const f16* WtV = WtH + ((size_t)(n * 3 + 1) * P_ + 16 * w + fr) * H_ + 8 * q;
  const f16* WtQ = WtH + ((size_t)(n * 3 + 2) * P_ + 16 * w + fr) * H_ + 8 * q;

  f32x4 accK[4] = {}, accQ[4] = {}, accV[4] = {};

  stage(0, 0);
  for (int step = 0; step < 16; ++step) {
    __syncthreads();
    if (step < 15) stage((step + 1) * 64, (step + 1) & 1);
    const int bs = step & 1;
    const int k0 = step * 64;

    f16x8 xf[4][2];
    #pragma unroll
    for (int ss = 0; ss < 4; ++ss) {
      int row = 16 * ss + fr;
      #pragma unroll
      for (int ks = 0; ks < 2; ++ks) {
        int ch = ((q + 4 * ks) ^ (row & 7)) * 8;
        xf[ss][ks] = *(const f16x8*)&xls[bs][row * 64 + ch];
      }
    }
    f16x8 wk0 = ldh8(WtK + k0), wk1 = ldh8(WtK + k0 + 32);
    f16x8 wq0 = ldh8(WtQ + k0), wq1 = ldh8(WtQ + k0 + 32);
    f16x8 wv0 = ldh8(WtV + k0), wv1 = ldh8(WtV + k0 + 32);
    #pragma unroll
    for (int ss = 0; ss < 4; ++ss) {
      accK[ss] = mm16(wk0, xf[ss][0], accK[ss]);
      accK[ss] = mm16(wk1, xf[ss][1], accK[ss]);
      accQ[ss] = mm16(wq0, xf[ss][0], accQ[ss]);
      accQ[ss] = mm16(wq1, xf[ss][1], accQ[ss]);
      accV[ss] = mm16(xf[ss][0], wv0, accV[ss]);
      accV[ss] = mm16(xf[ss][1], wv1, accV[ss]);
    }
  }

  // K/Q epilogue: lane holds s = s0+16ss+fr, p = 16w+4q+c. Q pre-scaled 1/8.
  #pragma unroll
  for (int ss = 0; ss < 4; ++ss) {
    f16x4 hK, hQ;
    #pragma unroll
    for (int c = 0; c < 4; ++c) {
      hK[c] = (f16)accK[ss][c];
      hQ[c] = (f16)(accQ[ss][c] * 0.125f);
    }
    size_t off = ((size_t)bn * S_ + (s0 + 16 * ss + fr)) * P_ + 16 * w + 4 * q;
    *(f16x4*)(Kh + off) = hK;
    *(f16x4*)(Qh + off) = hQ;
  }
  // V epilogue: lane holds s = s0+16ss+4q+c, p = 16w+fr -> VT[p][s]
  #pragma unroll
  for (int ss = 0; ss < 4; ++ss) {
    f16x4 hV;
    #pragma unroll
    for (int c = 0; c < 4; ++c) hV[c] = (f16)accV[ss][c];
    size_t off = ((size_t)bn * P_ + (16 * w + fr)) * S_ + s0 + 16 * ss + 4 * q;
    *(f16x4*)(VTh + off) = hV;
  }
}

// ---------------------------------------------------------------------------
// Kernel 2: column sum-exp (Q pre-scaled, exp(s) direct). Per-lane
// accumulation, double-buffered K prefetch, no loop barriers.
// ---------------------------------------------------------------------------
__global__ __launch_bounds__(256) void stats_kernel(
    const f16* __restrict__ Kh, const f16* __restrict__ Qh,
    float* __restrict__ csuminv)
{
  __shared__ float zbuf[2 * 64];
  const int tid = threadIdx.x;
  const int bid = blockIdx.x;
  const int j0 = (bid & 31) * 64;
  const int bn = bid >> 5;
  const int w = tid >> 6, lane = tid & 63, q = lane >> 4, fr = lane & 15;
  const int jb = 32 * (w & 1), ih = w >> 1, ib0 = 32 * ih;

  f16x8 qf[2][2];
  #pragma unroll
  for (int jt = 0; jt < 2; ++jt)
    #pragma unroll
    for (int ks = 0; ks < 2; ++ks)
      qf[jt][ks] = ldh8(Qh + ((size_t)bn * S_ + (j0 + jb + 16 * jt + fr)) * P_ + 8 * q + 32 * ks);

  f32x4 z[2] = {};
  f16x8 kA[2][2], kB[2][2];

  auto loadK = [&](f16x8 (&kf)[2][2], int i0) {
    #pragma unroll
    for (int it = 0; it < 2; ++it)
      #pragma unroll
      for (int ks = 0; ks < 2; ++ks)
        kf[it][ks] = ldh8(Kh + ((size_t)bn * S_ + (i0 + ib0 + 16 * it + fr)) * P_ + 8 * q + 32 * ks);
  };
  auto step = [&](f16x8 (&kf)[2][2]) {
    f32x4 sc[2][2] = {};
    #pragma unroll
    for (int ks = 0; ks < 2; ++ks)
      #pragma unroll
      for (int jt = 0; jt < 2; ++jt)
        #pragma unroll
        for (int it = 0; it < 2; ++it)
          sc[jt][it] = mm16(qf[jt][ks], kf[it][ks], sc[jt][it]);
    #pragma unroll
    for (int jt = 0; jt < 2; ++jt)
      #pragma unroll
      for (int c = 0; c < 4; ++c)
        z[jt][c] += __expf(sc[jt][0][c]) + __expf(sc[jt][1][c]);
  };

  loadK(kA, 0);
  for (int i0 = 0; i0 < S_; i0 += 128) {
    loadK(kB, i0 + 64);
    step(kA);
    loadK(kA, (i0 + 128) & (S_ - 1));
    step(kB);
  }

  #pragma unroll
  for (int msk = 1; msk <= 8; msk <<= 1)
    #pragma unroll
    for (int jt = 0; jt < 2; ++jt)
      #pragma unroll
      for (int c = 0; c < 4; ++c)
        z[jt][c] += __shfl_xor(z[jt][c], msk, 64);

  if (fr == 0) {
    #pragma unroll
    for (int jt = 0; jt < 2; ++jt)
      *(f32x4*)&zbuf[ih * 64 + jb + 16 * jt + 4 * q] = z[jt];
  }
  __syncthreads();
  if (tid < 64)
    csuminv[(size_t)bn * S_ + j0 + tid] = 1.0f / (zbuf[tid] + zbuf[64 + tid]);
}

// ---------------------------------------------------------------------------
// Kernel 2.5: V' = mask ? zinv*V : 0 (in-place on VT); C[bn][p] = (1/S)*sum
// of masked-out V. grid = B*NH*16 blocks; wave per p-row.
// ---------------------------------------------------------------------------
__global__ __launch_bounds__(256) void scale_kernel(
    f16* __restrict__ VT, const float* __restrict__ csuminv,
    const int* __restrict__ mask, float* __restrict__ Cbuf)
{
  const int bid = blockIdx.x;
  const int bn = bid >> 4;
  const int b = bn >> 4;
  const int p = (bid & 15) * 4 + (threadIdx.x >> 6);
  const int lane = threadIdx.x & 63;
  f16* row = VT + ((size_t)bn * P_ + p) * S_;
  const float* zr = csuminv + (size_t)bn * S_;
  const int* mr = mask + (size_t)b * S_;
  float acc = 0.0f;
  #pragma unroll
  for (int k = 0; k < 4; ++k) {
    int s = (lane + 64 * k) * 8;
    f16x8 v = *(const f16x8*)(row + s);
    f32x4 z0 = ld4f(zr + s), z1 = ld4f(zr + s + 4);
    i32x4 m0 = *(const i32x4*)(mr + s), m1 = *(const i32x4*)(mr + s + 4);
    f16x8 o;
    #pragma unroll
    for (int e = 0; e < 4; ++e) {
      float fv = (float)v[e];
      if (m0[e] != 0) o[e] = (f16)(fv * z0[e]);
      else { o[e] = (f16)0.0f; acc += fv; }
      float fv2 = (float)v[e + 4];
      if (m1[e] != 0) o[e + 4] = (f16)(fv2 * z1[e]);
      else { o[e + 4] = (f16)0.0f; acc += fv2; }
    }
    *(f16x8*)(row + s) = o;
  }
  #pragma unroll
  for (int msk = 1; msk <= 32; msk <<= 1) acc += __shfl_xor(acc, msk, 64);
  if (lane == 0) Cbuf[bn * P_ + p] = acc * (1.0f / S_);
}

// ---------------------------------------------------------------------------
// Kernel 3: AV pass, barrier-free hot loop (wave-private E slices).
// Block=(bn, i-tile 64); wave w owns j-slices {T*128 + w*32}.
// ---------------------------------------------------------------------------
__global__ __launch_bounds__(256) void av_kernel(
    const f16* __restrict__ Kh, const f16* __restrict__ Qh,
    const f16* __restrict__ VT, const float* __restrict__ Cbuf,
    f16* __restrict__ hidh)
{
  __shared__ f16  elds[4][64 * 40];   // per-wave E slice, pitch 40 f16 (80 B)
  __shared__ float accl[64 * 68];     // [i][p] fp32 accumulator, pitch 68
  const int tid = threadIdx.x;
  const int bid = blockIdx.x;
  const int i0 = (bid & 31) * 64;
  const int bn = bid >> 5;
  const int b = bn >> 4, n = bn & 15;
  const int w = tid >> 6, lane = tid & 63, q = lane >> 4, fr = lane & 15;
  f16* ew = &elds[w][0];

  // K b-frags fixed: rows i = i0+16it+fr (full 64-i tile)
  f16x8 kf[4][2];
  #pragma unroll
  for (int it = 0; it < 4; ++it)
    #pragma unroll
    for (int ks = 0; ks < 2; ++ks)
      kf[it][ks] = ldh8(Kh + ((size_t)bn * S_ + (i0 + 16 * it + fr)) * P_ + 8 * q + 32 * ks);

  f32x4 opv[4][4] = {};   // [pt][it]: p = 16pt+4q+c, i = 16it+fr

  for (int T = 0; T < S_ / 128; ++T) {
    const int j0 = T * 128 + w * 32;

    f16x8 aq[2][2];
    #pragma unroll
    for (int jt = 0; jt < 2; ++jt)
      #pragma unroll
      for (int ks = 0; ks < 2; ++ks)
        aq[jt][ks] = ldh8(Qh + ((size_t)bn * S_ + (j0 + 16 * jt + fr)) * P_ + 8 * q + 32 * ks);
    f16x8 va[4];
    #pragma unroll
    for (int pt = 0; pt < 4; ++pt)
      va[pt] = ldh8(VT + ((size_t)bn * P_ + (16 * pt + fr)) * S_ + j0 + 8 * q);

    #pragma unroll
    for (int it = 0; it < 4; ++it) {
      f32x4 s0 = {}, s1 = {};
      s0 = mm16(aq[0][0], kf[it][0], s0);
      s0 = mm16(aq[0][1], kf[it][1], s0);
      s1 = mm16(aq[1][0], kf[it][0], s1);
      s1 = mm16(aq[1][1], kf[it][1], s1);
      f16x4 e0, e1;
      #pragma unroll
      for (int c = 0; c < 4; ++c) {
        e0[c] = (f16)__expf(s0[c]);
        e1[c] = (f16)__expf(s1[c]);
      }
      *(f16x4*)(ew + (16 * it + fr) * 40 + 4 * q)      = e0;
      *(f16x4*)(ew + (16 * it + fr) * 40 + 16 + 4 * q) = e1;
    }

    #pragma unroll
    for (int it = 0; it < 4; ++it) {
      f16x8 ef = *(const f16x8*)(ew + (16 * it + fr) * 40 + 8 * q);
      #pragma unroll
      for (int pt = 0; pt < 4; ++pt)
        opv[pt][it] = mm16(va[pt], ef, opv[pt][it]);
    }
  }

  // ---- epilogue: reduce 4 wave-partials via LDS ----
  #pragma unroll
  for (int r = 0; r < 4; ++r) {
    __syncthreads();
    if (w == r) {
      #pragma unroll
      for (int it = 0; it < 4; ++it)
        #pragma unroll
        for (int pt = 0; pt < 4; ++pt) {
          float* a = &accl[(16 * it + fr) * 68 + 16 * pt + 4 * q];
          if (r == 0) *(f32x4*)a = opv[pt][it];
          else {
            f32x4 old = *(const f32x4*)a;
            #pragma unroll
            for (int c = 0; c < 4; ++c) old[c] += opv[pt][it][c];
            *(f32x4*)a = old;
          }
        }
    }
  }
  __syncthreads();

  const int ti = tid >> 2;
  const int tp = (tid & 3) << 4;
  const float* cb = Cbuf + bn * P_ + tp;
  f16* dst = hidh + ((size_t)b * S_ + (i0 + ti)) * H_ + n * P_ + tp;
  #pragma unroll
  for (int h = 0; h < 2; ++h) {
    f32x4 a0 = *(const f32x4*)&accl[ti * 68 + tp + 8 * h];
    f32x4 a1 = *(const f32x4*)&accl[ti * 68 + tp + 8 * h + 4];
    f32x4 c0 = ld4f(cb + 8 * h);
    f32x4 c1 = ld4f(cb + 8 * h + 4);
    f16x8 o;
    #pragma unroll
    for (int e = 0; e < 4; ++e) {
      o[e]     = (f16)(a0[e] + c0[e]);
      o[e + 4] = (f16)(a1[e] + c1[e]);
    }
    *(f16x8*)(dst + 8 * h) = o;
  }
}

// ---------------------------------------------------------------------------
// Kernel 4: out = hid @ Wl.T + bl via fp16 MFMA. hid tile staged in LDS.
// ---------------------------------------------------------------------------
__global__ __launch_bounds__(256) void final_kernel(
    const f16* __restrict__ hidh, const f16* __restrict__ WlH,
    const float* __restrict__ bl, float* __restrict__ out)
{
  __shared__ f16 hl[2][64 * 32];
  const int tid = threadIdx.x;
  const int ot = blockIdx.x & 15;
  const int rt = blockIdx.x >> 4;
  const int r0 = rt * 64, o0 = ot * 64;
  const int w = tid >> 6, lane = tid & 63, q = lane >> 4, fr = lane & 15;

  const int srow = tid >> 2, scc = tid & 3;
  const f16* hsrc = hidh + (size_t)(r0 + srow) * H_ + 8 * scc;
  const int saddr = srow * 32 + ((scc ^ (srow & 3)) * 8);

  auto stage = [&](int k0, int bufsel) {
    *(f16x8*)&hl[bufsel][saddr] = ldh8(hsrc + k0);
  };

  const f16* WlA = WlH + ((size_t)(o0 + 16 * w + fr)) * H_ + 8 * q;

  f32x4 acc[4] = {};

  stage(0, 0);
  for (int step = 0; step < 32; ++step) {
    __syncthreads();
    if (step < 31) stage((step + 1) * 32, (step + 1) & 1);
    const int bs = step & 1;
    const int k0 = step * 32;

    f16x8 bh[4];
    #pragma unroll
    for (int ss = 0; ss < 4; ++ss) {
      int addr = (16 * ss + fr) * 32 + ((q ^ (fr & 3)) * 8);
      bh[ss] = *(const f16x8*)&hl[bs][addr];
    }
    f16x8 ah = ldh8(WlA + k0);
    #pragma unroll
    for (int ss = 0; ss < 4; ++ss)
      acc[ss] = mm16(ah, bh[ss], acc[ss]);
  }

  const int o = o0 + 16 * w + 4 * q;
  f32x4 bv = ld4f(bl + o);
  #pragma unroll
  for (int ss = 0; ss < 4; ++ss) {
    f32x4 v;
    #pragma unroll
    for (int c = 0; c < 4; ++c) v[c] = acc[ss][c] + bv[c];
    *(f32x4*)(out + (size_t)(r0 + 16 * ss + fr) * H_ + o) = v;
  }
}

// ---------------------------------------------------------------------------
extern "C" void kernel_launch(void* const* d_in, const int* in_sizes, int n_in,
                              void* d_out, int out_size, void* d_ws, size_t ws_size,
                              hipStream_t stream) {
  const float* x    = (const float*)d_in[0];
  const int*   mask = (const int*)d_in[1];
  const float* W    = (const float*)d_in[2];
  const float* Wl   = (const float*)d_in[3];
  const float* bl   = (const float*)d_in[4];
  float* out = (float*)d_out;

  const size_t SZ  = (size_t)B_ * NH_ * S_ * P_;      // 4,194,304
  const size_t SZW = (size_t)NH_ * 3 * H_ * P_;       // 3,145,728
  const size_t SZL = (size_t)H_ * H_;                 // 1,048,576
  const size_t SZC = (size_t)B_ * NH_ * S_;           // 65,536
  const size_t SZH = (size_t)B_ * S_ * H_;            // 4,194,304

  char* p = (char*)d_ws;
  f16*   Kh   = (f16*)p;  p += SZ * 2;
  f16*   Qh   = (f16*)p;  p += SZ * 2;
  f16*   VTh  = (f16*)p;  p += SZ * 2;
  f16*   WtH  = (f16*)p;  p += SZW * 2;
  f16*   WlH  = (f16*)p;  p += SZL * 2;
  f16*   hidh = (f16*)p;  p += SZH * 2;
  float* csuminv = (float*)p; p += SZC * 4;
  float* Cbuf    = (float*)p; p += (size_t)B_ * NH_ * P_ * 4;
  // total ~42.9 MB

  tw_kernel   <<<NH_ * 3 * (H_ / 64), 256, 0, stream>>>(W, WtH);
  swl_kernel  <<<(SZL / 4) / 256, 256, 0, stream>>>(Wl, WlH);
  qkv_kernel  <<<B_ * NH_ * (S_ / 64), 256, 0, stream>>>(x, WtH, Kh, Qh, VTh);
  stats_kernel<<<B_ * NH_ * (S_ / 64), 256, 0, stream>>>(Kh, Qh, csuminv);
  scale_kernel<<<B_ * NH_ * 16, 256, 0, stream>>>(VTh, csuminv, mask, Cbuf);
  av_kernel   <<<B_ * NH_ * (S_ / 64), 256, 0, stream>>>(
      Kh, Qh, VTh, Cbuf, hidh);
  final_kernel<<<(B_ * S_ / 64) * (H_ / 64), 256, 0, stream>>>(
      hidh, WlH, bl, out);
}